// Round 3
// baseline (70.055 us; speedup 1.0000x reference)
//
#include <hip/hip_runtime.h>
#include <math.h>

// ---------------- workspace layout (float offsets) ----------------
#define WS_HXPART 0          // [8 chunk][8 n][256 j] partials of x@g1_lin[:510]
#define WS_HE1    16384      // [24][256]
#define WS_HE2    22528      // [24][64]
#define WS_WF     24064      // [128][10] fused c2l1w@c2l2w
#define WS_BF     25344      // [10]
#define WS_VM     25354      // [3][64] means: x2 / ea_new even / ea_new odd
#define WS_FLAGS  25600      // int flags (zeroed via hipMemsetAsync each call)

// smem carve (floats); total 15964 = 63.8 KB
#define SMEM_FLOATS 15964

__device__ __forceinline__ void block_signal(int* flag) {
    __syncthreads();                 // all block's global writes drained (vmcnt0)
    __threadfence();                 // agent-scope release: writeback L2
    if (threadIdx.x == 0)
        __hip_atomic_fetch_add(flag, 1, __ATOMIC_RELEASE, __HIP_MEMORY_SCOPE_AGENT);
}
__device__ __forceinline__ void block_wait(int* flag, int target) {
    if (threadIdx.x == 0)
        while (__hip_atomic_load(flag, __ATOMIC_ACQUIRE, __HIP_MEMORY_SCOPE_AGENT) < target)
            __builtin_amdgcn_s_sleep(1);
    __syncthreads();
    __threadfence();                 // agent-scope acquire: invalidate L1/L2 for fresh data
}

__global__ __launch_bounds__(256) void fused_dtgnn(
    const float* __restrict__ xf,   const float* __restrict__ xft,
    const float* __restrict__ ea,
    const float* __restrict__ c1w1, const float* __restrict__ c1b1,
    const float* __restrict__ c1w2, const float* __restrict__ c1b2,
    const float* __restrict__ g1lin,
    const float* __restrict__ g1as, const float* __restrict__ g1ad,
    const float* __restrict__ g1le, const float* __restrict__ g1ae,
    const float* __restrict__ g1b,
    const float* __restrict__ g2lin,
    const float* __restrict__ g2as, const float* __restrict__ g2ad,
    const float* __restrict__ g2le, const float* __restrict__ g2ae,
    const float* __restrict__ g2b,
    const float* __restrict__ mw1,  const float* __restrict__ mb1,
    const float* __restrict__ mw2,  const float* __restrict__ mb2,
    const float* __restrict__ d1w,  const float* __restrict__ d1b,
    const float* __restrict__ d2w,  const float* __restrict__ d2b,
    const float* __restrict__ d3w,  const float* __restrict__ d3b,
    const float* __restrict__ c2w1, const float* __restrict__ c2b1,
    const float* __restrict__ c2w2, const float* __restrict__ c2b2,
    const float* __restrict__ l1w,  const float* __restrict__ l1b,
    const float* __restrict__ l2w,  const float* __restrict__ l2b,
    const int* __restrict__ eidx,
    float* __restrict__ ws, float* __restrict__ out)
{
    __shared__ float smem[SMEM_FLOATS];
    const int b = blockIdx.x, tid = threadIdx.x;
    int* F_GAT = (int*)(ws + WS_FLAGS);       // target 13 = 8 HX + 4 HE1 + 1 (b13 HE2)
    int* F_FIN = (int*)(ws + WS_FLAGS) + 1;   // target 6  = 1 (b12) + 1 (b13 means) + 4 WF

    if (b < 8) {
        // ---------- HX partials: chunk b of x_feat @ g1_lin[:510] ----------
        float* sx = smem;                     // [8][64]
        const int k0 = b * 64;
        const int klen = (b == 7) ? 62 : 64;
        for (int idx = tid; idx < 512; idx += 256) {
            int n = idx >> 6, kk = idx & 63;
            sx[n * 64 + kk] = (kk < klen) ? xf[n * 510 + k0 + kk] : 0.f;
        }
        __syncthreads();
        float acc[8];
        #pragma unroll
        for (int n = 0; n < 8; ++n) acc[n] = 0.f;
        for (int kk = 0; kk < 64; ++kk) {
            float w = g1lin[(k0 + kk) * 256 + tid];
            #pragma unroll
            for (int n = 0; n < 8; ++n) acc[n] += sx[n * 64 + kk] * w;
        }
        #pragma unroll
        for (int n = 0; n < 8; ++n) ws[WS_HXPART + (b * 8 + n) * 256 + tid] = acc[n];
        block_signal(F_GAT);
    } else if (b < 12) {
        // ---------- HE1 = [edge_attr ; mean] @ g1_le, 64-col chunk ----------
        float* sea = smem;                    // [17][128]
        for (int idx = tid; idx < 2048; idx += 256) sea[idx] = ea[idx];
        __syncthreads();
        if (tid < 128) {
            float m = 0.f;
            for (int e = 0; e < 16; ++e) m += sea[e * 128 + tid];
            sea[16 * 128 + tid] = m * (1.f / 16.f);
        }
        __syncthreads();
        const int cc = b - 8;
        for (int o = tid; o < 1536; o += 256) {
            int e = o >> 6, j = cc * 64 + (o & 63);
            int row = (e < 16) ? e : 16;
            float acc = 0.f;
            for (int k = 0; k < 128; ++k) acc += sea[row * 128 + k] * g1le[k * 256 + j];
            ws[WS_HE1 + e * 256 + j] = acc;
        }
        block_signal(F_GAT);
    } else if (b == 12) {
        // ---------- CNN_1, then the serial GAT1->GAT2 chain ----------
        float* h   = smem;          float* x1  = smem + 2048;
        float* h2  = smem + 4096;   float* x2  = smem + 4608;
        float* sxc = smem + 5120;
        float* ss1 = smem + 5136;   float* sd1 = smem + 5168;
        float* se1 = smem + 5200;   float* al1 = smem + 5296;
        float* wt1 = smem + 5392;   float* mx1 = smem + 5488;  float* dn1 = smem + 5520;
        float* ss2 = smem + 5552;   float* sd2 = smem + 5560;
        float* se2 = smem + 5568;   float* al2 = smem + 5592;
        float* wt2 = smem + 5616;   float* mx2 = smem + 5640;  float* dn2 = smem + 5648;
        float* t2  = smem + 5656;   float* y1  = smem + 5816;  float* y2  = smem + 5976;
        int*   esrc = (int*)(smem + 5992);
        int*   edst = (int*)(smem + 6016);
        float* sg1as = smem + 6040; float* sg1ad = smem + 6296;
        float* sg1ae = smem + 6552; float* sg1b  = smem + 6808;
        float* sgl0  = smem + 7064; float* sgl1  = smem + 7320;
        float* sg2as = smem + 7576; float* sg2ad = smem + 7640;
        float* sg2ae = smem + 7704; float* sg2b  = smem + 7768;

        // CNN_1 (same math as the verified 4-kernel version)
        if (tid < 160) {
            int b_ = tid / 80, ch = (tid % 80) / 10, tt = tid % 10;
            int srow = ((ch & 1) == 0) ? 1 : 5;
            int n = 4 * b_ + (ch >> 1);
            t2[tid] = xft[srow * 80 + n * 10 + tt];
        }
        __syncthreads();
        if (tid < 160) {
            int b_ = tid / 80, co = (tid % 80) / 10, tt = tid % 10;
            float acc = c1b1[co];
            for (int ci = 0; ci < 8; ++ci)
                for (int k = 0; k < 3; ++k) {
                    int p = tt + k - 1;
                    if (p >= 0 && p < 10) acc += t2[b_ * 80 + ci * 10 + p] * c1w1[co * 24 + ci * 3 + k];
                }
            y1[tid] = fmaxf(acc, 0.f);
        }
        __syncthreads();
        if (tid < 16) {
            int b_ = tid >> 3, p = tid & 7;
            float acc = c1b2[0];
            for (int i = 0; i < 10; ++i)
                for (int k = 0; k < 3; ++k) {
                    int q = p + k - 1;
                    if (q >= 0 && q < 8) acc += y1[b_ * 80 + q * 10 + i] * c1w2[i * 3 + k];
                }
            y2[tid] = acc;
        }
        if (tid < 16) sxc[tid] = fmaxf(y2[tid], 0.f);
        // prefetch attention weights into LDS while producers run
        sg1as[tid] = g1as[tid]; sg1ad[tid] = g1ad[tid];
        sg1ae[tid] = g1ae[tid]; sg1b[tid]  = g1b[tid];
        sgl0[tid] = g1lin[510 * 256 + tid]; sgl1[tid] = g1lin[511 * 256 + tid];
        if (tid < 64) { sg2as[tid] = g2as[tid]; sg2ad[tid] = g2ad[tid];
                        sg2ae[tid] = g2ae[tid]; sg2b[tid]  = g2b[tid]; }
        if (tid < 16)       { esrc[tid] = eidx[tid]; edst[tid] = eidx[16 + tid]; }
        else if (tid < 24)  { esrc[tid] = tid - 16;  edst[tid] = tid - 16; }

        block_wait(F_GAT, 13);

        // h[n][j] = sum of partials + CNN rows
        for (int n = 0; n < 8; ++n) {
            float acc = 0.f;
            #pragma unroll
            for (int cb = 0; cb < 8; ++cb) acc += ws[WS_HXPART + (cb * 8 + n) * 256 + tid];
            acc += sxc[n * 2] * sgl0[tid] + sxc[n * 2 + 1] * sgl1[tid];
            h[n * 256 + tid] = acc;
        }
        __syncthreads();
        if (tid < 32) {
            int n = tid >> 2, hd = tid & 3;
            float aS = 0.f, aD = 0.f;
            for (int c = 0; c < 64; ++c) {
                float hv = h[n * 256 + hd * 64 + c];
                aS += hv * sg1as[hd * 64 + c];
                aD += hv * sg1ad[hd * 64 + c];
            }
            ss1[tid] = aS; sd1[tid] = aD;
        } else if (tid < 128) {
            int idx = tid - 32;
            int e = idx >> 2, hd = idx & 3;
            float acc = 0.f;
            for (int c = 0; c < 64; ++c) acc += ws[WS_HE1 + e * 256 + hd * 64 + c] * sg1ae[hd * 64 + c];
            se1[idx] = acc;
        }
        __syncthreads();
        if (tid < 96) {
            int e = tid >> 2, hd = tid & 3;
            float s = ss1[esrc[e] * 4 + hd] + sd1[edst[e] * 4 + hd] + se1[tid];
            al1[tid] = (s > 0.f) ? s : 0.2f * s;
        }
        __syncthreads();
        if (tid < 32) {
            int n = tid >> 2, hd = tid & 3;
            float mx = -1e30f;
            for (int e = 0; e < 24; ++e) if (edst[e] == n) mx = fmaxf(mx, al1[e * 4 + hd]);
            float dn = 0.f;
            for (int e = 0; e < 24; ++e) if (edst[e] == n) dn += expf(al1[e * 4 + hd] - mx);
            mx1[tid] = mx; dn1[tid] = dn;
        }
        __syncthreads();
        if (tid < 96) {
            int e = tid >> 2, hd = tid & 3, d = edst[e];
            wt1[tid] = expf(al1[tid] - mx1[d * 4 + hd]) / (dn1[d * 4 + hd] + 1e-16f);
        }
        __syncthreads();
        {   // aggregate + bias + relu -> x1
            const int hd = tid >> 6;
            for (int n = 0; n < 8; ++n) {
                float acc = 0.f;
                for (int e = 0; e < 24; ++e)
                    if (edst[e] == n) acc += wt1[e * 4 + hd] * h[esrc[e] * 256 + tid];
                x1[n * 256 + tid] = fmaxf(acc + sg1b[tid], 0.f);
            }
        }
        __syncthreads();
        {   // h2 = x1 @ g2_lin (g2lin streamed from cache)
            int c = tid & 63, n0 = tid >> 6;
            for (int half = 0; half < 2; ++half) {
                int n = n0 + half * 4;
                float acc = 0.f;
                for (int k = 0; k < 256; ++k) acc += x1[n * 256 + k] * g2lin[k * 64 + c];
                h2[n * 64 + c] = acc;
            }
        }
        __syncthreads();
        if (tid < 8) {
            float aS = 0.f, aD = 0.f;
            for (int c = 0; c < 64; ++c) {
                float hv = h2[tid * 64 + c];
                aS += hv * sg2as[c]; aD += hv * sg2ad[c];
            }
            ss2[tid] = aS; sd2[tid] = aD;
        } else if (tid < 32) {
            int e = tid - 8;
            float acc = 0.f;
            for (int c = 0; c < 64; ++c) acc += ws[WS_HE2 + e * 64 + c] * sg2ae[c];
            se2[e] = acc;
        }
        __syncthreads();
        if (tid < 24) {
            float s = ss2[esrc[tid]] + sd2[edst[tid]] + se2[tid];
            al2[tid] = (s > 0.f) ? s : 0.2f * s;
        }
        __syncthreads();
        if (tid < 8) {
            float mx = -1e30f;
            for (int e = 0; e < 24; ++e) if (edst[e] == tid) mx = fmaxf(mx, al2[e]);
            float dn = 0.f;
            for (int e = 0; e < 24; ++e) if (edst[e] == tid) dn += expf(al2[e] - mx);
            mx2[tid] = mx; dn2[tid] = dn;
        }
        __syncthreads();
        if (tid < 24) {
            int d = edst[tid];
            wt2[tid] = expf(al2[tid] - mx2[d]) / (dn2[d] + 1e-16f);
        }
        __syncthreads();
        {
            int c = tid & 63, n0 = tid >> 6;
            for (int half = 0; half < 2; ++half) {
                int n = n0 + half * 4;
                float acc = 0.f;
                for (int e = 0; e < 24; ++e)
                    if (edst[e] == n) acc += wt2[e] * h2[esrc[e] * 64 + c];
                x2[n * 64 + c] = fmaxf(acc + sg2b[c], 0.f);
            }
        }
        __syncthreads();
        if (tid < 64) {
            float m = 0.f;
            for (int n = 0; n < 8; ++n) m += x2[n * 64 + tid];
            ws[WS_VM + tid] = m * 0.125f;
        }
        block_signal(F_FIN);
    } else if (b == 13) {
        // ---------- edge MLP -> ea_new ; even/odd means ; HE2 ----------
        float* sea = smem;          // 2048
        float* tmp = smem + 2048;   // 1024
        float* ean = smem + 3072;   // [17][64]
        for (int idx = tid; idx < 2048; idx += 256) sea[idx] = ea[idx];
        __syncthreads();
        for (int o = tid; o < 1024; o += 256) {
            int e = o >> 6, c = o & 63;
            float acc = mb1[c];
            for (int k = 0; k < 128; ++k) acc += sea[e * 128 + k] * mw1[k * 64 + c];
            tmp[o] = fmaxf(acc, 0.f);
        }
        __syncthreads();
        for (int o = tid; o < 1024; o += 256) {
            int e = o >> 6, c = o & 63;
            float acc = mb2[c];
            for (int k = 0; k < 64; ++k) acc += tmp[e * 64 + k] * mw2[k * 64 + c];
            ean[o] = acc;
        }
        __syncthreads();
        if (tid < 64) {                           // self-loop fill row (mean of 16)
            float m = 0.f;
            for (int e = 0; e < 16; ++e) m += ean[e * 64 + tid];
            ean[1024 + tid] = m * (1.f / 16.f);
        } else if (tid < 128) {                   // even mean -> VM[64..127]
            int c = tid - 64;
            float m = 0.f;
            for (int e = 0; e < 16; e += 2) m += ean[e * 64 + c];
            ws[WS_VM + 64 + c] = m * 0.125f;
        } else if (tid < 192) {                   // odd mean -> VM[128..191]
            int c = tid - 128;
            float m = 0.f;
            for (int e = 1; e < 16; e += 2) m += ean[e * 64 + c];
            ws[WS_VM + 128 + c] = m * 0.125f;
        }
        __syncthreads();
        for (int o = tid; o < 1536; o += 256) {   // HE2 = [ea_new ; mean] @ g2_le
            int e = o >> 6, c = o & 63;
            int row = (e < 16) ? e : 16;
            float acc = 0.f;
            for (int k = 0; k < 64; ++k) acc += ean[row * 64 + k] * g2le[k * 64 + c];
            ws[WS_HE2 + o] = acc;
        }
        __syncthreads();
        __threadfence();
        if (tid == 0) {
            __hip_atomic_fetch_add(F_GAT, 1, __ATOMIC_RELEASE, __HIP_MEMORY_SCOPE_AGENT);
            __hip_atomic_fetch_add(F_FIN, 1, __ATOMIC_RELEASE, __HIP_MEMORY_SCOPE_AGENT);
        }
    } else if (b < 18) {
        // ---------- fused tail linear: wf = c2l1w @ c2l2w (+ bf on b14) ----------
        float* sl2 = smem;                        // 2560
        for (int idx = tid; idx < 2560; idx += 256) sl2[idx] = l2w[idx];
        __syncthreads();
        const int m0 = (b - 14) * 32;
        for (int o = tid; o < 320; o += 256) {
            int ml = o / 10, t = o % 10, m = m0 + ml;
            float acc = 0.f;
            for (int j = 0; j < 256; ++j) acc += l1w[m * 256 + j] * sl2[j * 10 + t];
            ws[WS_WF + m * 10 + t] = acc;
        }
        if (b == 14 && tid < 10) {
            float acc = l2b[tid];
            for (int j = 0; j < 256; ++j) acc += l1b[j] * sl2[j * 10 + tid];
            ws[WS_BF + tid] = acc;
        }
        block_signal(F_FIN);
    } else {
        // ---------- deconv (LDS-local) + CNN_2 + fused linear, 4 rows/block ----------
        const int r0 = (b - 18) * 4;
        float* sA   = smem;           // 7680: [3][64][4][10] deconv slice; later u/v/f
        float* sw2s = smem + 7680;    // 6144
        float* sw1s = smem + 13824;   // 384
        float* swfs = smem + 14208;   // 1280
        float* cins = smem + 15488;   // [4][4][10]
        float* vms  = smem + 15648;   // 192
        float* sb1  = smem + 15840;   // 32
        float* sb2  = smem + 15872;   // 64
        float* sbfs = smem + 15936;   // 16
        float* sdb  = smem + 15952;   // 12: deconv bias per (tau, rl)

        for (int idx = tid; idx < 7680; idx += 256) {
            int t = idx % 10, rl = (idx / 10) & 3, ii = idx / 40;
            int tau = ii >> 6, i = ii & 63;
            const float* dw = (tau == 0) ? d1w : (tau == 1) ? d2w : d3w;
            sA[idx] = dw[i * 640 + (r0 + rl) * 10 + t];
        }
        for (int idx = tid; idx < 6144; idx += 256) sw2s[idx] = c2w2[idx];
        for (int idx = tid; idx < 384; idx += 256) sw1s[idx] = c2w1[idx];
        if (tid < 32) sb1[tid] = c2b1[tid];
        if (tid < 64) sb2[tid] = c2b2[tid];
        if (tid < 40) { int rl = tid / 10, t = tid % 10; cins[rl * 40 + 10 + t] = xft[(r0 + rl) * 10 + t]; }
        if (tid < 12) {
            int tau = tid / 4, rl = tid % 4;
            const float* db = (tau == 0) ? d1b : (tau == 1) ? d2b : d3b;
            sdb[tid] = db[r0 + rl];
        }

        block_wait(F_FIN, 6);
        for (int idx = tid; idx < 1280; idx += 256) swfs[idx] = ws[WS_WF + idx];
        if (tid < 192) vms[tid] = ws[WS_VM + tid];
        if (tid < 10)  sbfs[tid] = ws[WS_BF + tid];
        __syncthreads();

        if (tid < 120) {                          // deconv: 4 rl x 3 tau x 10 t
            int t = tid % 10, tau = (tid / 10) % 3, rl = tid / 30;
            float acc = sdb[tau * 4 + rl];
            for (int i = 0; i < 64; ++i)
                acc += vms[tau * 64 + i] * sA[((tau * 64 + i) * 4 + rl) * 10 + t];
            int ch = (tau == 0) ? 0 : (tau + 1);  // tau0->ch0(x_pool), tau1->ch2(ef), tau2->ch3(er)
            cins[rl * 40 + ch * 10 + t] = acc;
        }
        __syncthreads();
        float* u = sA; float* v = sA + 2048; float* f = sA + 3072;  // alias dead sA
        for (int o = tid; o < 1024; o += 256) {   // conv1, pad 0
            int rl = o >> 8, co = (o >> 3) & 31, p = o & 7;
            float acc = sb1[co];
            #pragma unroll
            for (int ci = 0; ci < 4; ++ci)
                #pragma unroll
                for (int k = 0; k < 3; ++k)
                    acc += cins[rl * 40 + ci * 10 + p + k] * sw1s[co * 12 + ci * 3 + k];
            u[o] = acc;
        }
        __syncthreads();
        for (int o = tid; o < 512; o += 256) {    // maxpool(2)
            int rl = o >> 7, co = (o >> 2) & 31, q = o & 3;
            v[o] = fmaxf(u[rl * 256 + co * 8 + 2 * q], u[rl * 256 + co * 8 + 2 * q + 1]);
        }
        __syncthreads();
        for (int o = tid; o < 512; o += 256) {    // conv2 + flatten
            int rl = o >> 7, m = o & 127, co2 = m >> 1, p = m & 1;
            float acc = sb2[co2];
            for (int ci = 0; ci < 32; ++ci)
                #pragma unroll
                for (int k = 0; k < 3; ++k)
                    acc += v[rl * 128 + ci * 4 + p + k] * sw2s[co2 * 96 + ci * 3 + k];
            f[rl * 128 + m] = acc;
        }
        __syncthreads();
        if (tid < 40) {                           // fused (l1->l2) + relu -> out
            int rl = tid / 10, t = tid % 10;
            float acc = sbfs[t];
            for (int m = 0; m < 128; ++m) acc += f[rl * 128 + m] * swfs[m * 10 + t];
            out[(r0 + rl) * 10 + t] = fmaxf(acc, 0.f);
        }
    }
}

extern "C" void kernel_launch(void* const* d_in, const int* in_sizes, int n_in,
                              void* d_out, int out_size, void* d_ws, size_t ws_size,
                              hipStream_t stream)
{
    const float* xf    = (const float*)d_in[0];
    const float* xft   = (const float*)d_in[1];
    const float* ea    = (const float*)d_in[2];
    const float* c1w1  = (const float*)d_in[3];
    const float* c1b1  = (const float*)d_in[4];
    const float* c1w2  = (const float*)d_in[5];
    const float* c1b2  = (const float*)d_in[6];
    const float* g1lin = (const float*)d_in[7];
    const float* g1as  = (const float*)d_in[8];
    const float* g1ad  = (const float*)d_in[9];
    const float* g1le  = (const float*)d_in[10];
    const float* g1ae  = (const float*)d_in[11];
    const float* g1b   = (const float*)d_in[12];
    const float* g2lin = (const float*)d_in[13];
    const float* g2as  = (const float*)d_in[14];
    const float* g2ad  = (const float*)d_in[15];
    const float* g2le  = (const float*)d_in[16];
    const float* g2ae  = (const float*)d_in[17];
    const float* g2b   = (const float*)d_in[18];
    const float* mw1   = (const float*)d_in[19];
    const float* mb1   = (const float*)d_in[20];
    const float* mw2   = (const float*)d_in[21];
    const float* mb2   = (const float*)d_in[22];
    const float* d1w   = (const float*)d_in[23];
    const float* d1b   = (const float*)d_in[24];
    const float* d2w   = (const float*)d_in[25];
    const float* d2b   = (const float*)d_in[26];
    const float* d3w   = (const float*)d_in[27];
    const float* d3b   = (const float*)d_in[28];
    const float* c2w1  = (const float*)d_in[29];
    const float* c2b1  = (const float*)d_in[30];
    const float* c2w2  = (const float*)d_in[31];
    const float* c2b2  = (const float*)d_in[32];
    const float* l1w   = (const float*)d_in[33];
    const float* l1b   = (const float*)d_in[34];
    const float* l2w   = (const float*)d_in[35];
    const float* l2b   = (const float*)d_in[36];
    const int*   eidx  = (const int*)d_in[37];
    float* ws  = (float*)d_ws;
    float* out = (float*)d_out;

    // Flags must start at 0 every call (ws is poisoned 0xAA once and never
    // re-poisoned between replays while our counters mutate).
    hipMemsetAsync((char*)d_ws + WS_FLAGS * sizeof(float), 0, 64, stream);

    hipLaunchKernelGGL(fused_dtgnn, dim3(34), dim3(256), 0, stream,
        xf, xft, ea, c1w1, c1b1, c1w2, c1b2,
        g1lin, g1as, g1ad, g1le, g1ae, g1b,
        g2lin, g2as, g2ad, g2le, g2ae, g2b,
        mw1, mb1, mw2, mb2,
        d1w, d1b, d2w, d2b, d3w, d3b,
        c2w1, c2b1, c2w2, c2b2,
        l1w, l1b, l2w, l2b, eidx, ws, out);
}

// Round 4
// 57.735 us; speedup vs baseline: 1.2134x; 1.2134x over previous
//
#include <hip/hip_runtime.h>
#include <math.h>

// ---------------- workspace layout (float offsets) ----------------
#define WS_HXPART 0          // [8 chunk][8 n][256 j] partials of x@g1_lin[:510]
#define WS_HE1    16384      // [24][256]
#define WS_HE2    22528      // [24][64]
#define WS_WF     24064      // [128][10] fused c2l1w@c2l2w
#define WS_BF     25344      // [10]
#define WS_VM     25354      // [3][64] means: x2 / ea_new even / ea_new odd

// ================= K1: parallel precompute (17 blocks x 256) =================
__global__ __launch_bounds__(256) void k1_pre(
    const float* __restrict__ xf,   const float* __restrict__ ea,
    const float* __restrict__ g1lin,const float* __restrict__ g1le,
    const float* __restrict__ mw1,  const float* __restrict__ mb1,
    const float* __restrict__ mw2,  const float* __restrict__ mb2,
    const float* __restrict__ g2le,
    const float* __restrict__ l1w,  const float* __restrict__ l1b,
    const float* __restrict__ l2w,  const float* __restrict__ l2b,
    float* __restrict__ ws)
{
    const int b = blockIdx.x, tid = threadIdx.x;
    if (b < 8) {
        // ---------- HX partials: chunk b of x_feat @ g1_lin[:510] ----------
        __shared__ float sx[512];             // [8][64]
        const int k0 = b * 64;
        const int klen = (b == 7) ? 62 : 64;
        for (int idx = tid; idx < 512; idx += 256) {
            int n = idx >> 6, kk = idx & 63;
            sx[n * 64 + kk] = (kk < klen) ? xf[n * 510 + k0 + kk] : 0.f;
        }
        __syncthreads();
        float acc[8];
        #pragma unroll
        for (int n = 0; n < 8; ++n) acc[n] = 0.f;
        for (int kk = 0; kk < 64; ++kk) {
            float w = g1lin[(k0 + kk) * 256 + tid];
            #pragma unroll
            for (int n = 0; n < 8; ++n) acc[n] += sx[n * 64 + kk] * w;
        }
        #pragma unroll
        for (int n = 0; n < 8; ++n) ws[WS_HXPART + (b * 8 + n) * 256 + tid] = acc[n];
    } else if (b < 12) {
        // ---------- HE1 = [edge_attr ; mean] @ g1_le, 64-col chunk ----------
        __shared__ float sea[17 * 128];
        for (int idx = tid; idx < 2048; idx += 256) sea[idx] = ea[idx];
        __syncthreads();
        if (tid < 128) {
            float m = 0.f;
            for (int e = 0; e < 16; ++e) m += sea[e * 128 + tid];
            sea[16 * 128 + tid] = m * (1.f / 16.f);
        }
        __syncthreads();
        const int cc = b - 8;
        for (int o = tid; o < 1536; o += 256) {
            int e = o >> 6, j = cc * 64 + (o & 63);
            int row = (e < 16) ? e : 16;
            float acc = 0.f;
            for (int k = 0; k < 128; ++k) acc += sea[row * 128 + k] * g1le[k * 256 + j];
            ws[WS_HE1 + e * 256 + j] = acc;
        }
    } else if (b == 12) {
        // ---------- edge MLP -> ea_new ; even/odd means ; HE2 ----------
        __shared__ float sea[2048];
        __shared__ float tmp[1024];
        __shared__ float ean[17 * 64];
        for (int idx = tid; idx < 2048; idx += 256) sea[idx] = ea[idx];
        __syncthreads();
        for (int o = tid; o < 1024; o += 256) {
            int e = o >> 6, c = o & 63;
            float acc = mb1[c];
            for (int k = 0; k < 128; ++k) acc += sea[e * 128 + k] * mw1[k * 64 + c];
            tmp[o] = fmaxf(acc, 0.f);
        }
        __syncthreads();
        for (int o = tid; o < 1024; o += 256) {
            int e = o >> 6, c = o & 63;
            float acc = mb2[c];
            for (int k = 0; k < 64; ++k) acc += tmp[e * 64 + k] * mw2[k * 64 + c];
            ean[o] = acc;
        }
        __syncthreads();
        if (tid < 64) {                           // self-loop fill row (mean of 16)
            float m = 0.f;
            for (int e = 0; e < 16; ++e) m += ean[e * 64 + tid];
            ean[1024 + tid] = m * (1.f / 16.f);
        } else if (tid < 128) {                   // even mean -> VM[64..127]
            int c = tid - 64;
            float m = 0.f;
            for (int e = 0; e < 16; e += 2) m += ean[e * 64 + c];
            ws[WS_VM + 64 + c] = m * 0.125f;
        } else if (tid < 192) {                   // odd mean -> VM[128..191]
            int c = tid - 128;
            float m = 0.f;
            for (int e = 1; e < 16; e += 2) m += ean[e * 64 + c];
            ws[WS_VM + 128 + c] = m * 0.125f;
        }
        __syncthreads();
        for (int o = tid; o < 1536; o += 256) {   // HE2 = [ea_new ; mean] @ g2_le
            int e = o >> 6, c = o & 63;
            int row = (e < 16) ? e : 16;
            float acc = 0.f;
            for (int k = 0; k < 64; ++k) acc += ean[row * 64 + k] * g2le[k * 64 + c];
            ws[WS_HE2 + o] = acc;
        }
    } else {
        // ---------- fused tail linear: wf = c2l1w @ c2l2w (+ bf on b13) ----------
        __shared__ float sl2[2560];
        for (int idx = tid; idx < 2560; idx += 256) sl2[idx] = l2w[idx];
        __syncthreads();
        const int m0 = (b - 13) * 32;
        for (int o = tid; o < 320; o += 256) {
            int ml = o / 10, t = o % 10, m = m0 + ml;
            float acc = 0.f;
            for (int j = 0; j < 256; ++j) acc += l1w[m * 256 + j] * sl2[j * 10 + t];
            ws[WS_WF + m * 10 + t] = acc;
        }
        if (b == 13 && tid < 10) {
            float acc = l2b[tid];
            for (int j = 0; j < 256; ++j) acc += l1b[j] * sl2[j * 10 + tid];
            ws[WS_BF + tid] = acc;
        }
    }
}

// ================= K2: CNN_1 + GAT1 -> GAT2 -> x2 mean (1 block x 512) ========
__global__ __launch_bounds__(512) void k2_gat(
    const float* __restrict__ xft,
    const float* __restrict__ c1w1, const float* __restrict__ c1b1,
    const float* __restrict__ c1w2, const float* __restrict__ c1b2,
    const float* __restrict__ g1lin,
    const float* __restrict__ g1as, const float* __restrict__ g1ad,
    const float* __restrict__ g1ae, const float* __restrict__ g1b,
    const float* __restrict__ g2lin,
    const float* __restrict__ g2as, const float* __restrict__ g2ad,
    const float* __restrict__ g2ae, const float* __restrict__ g2b,
    const int* __restrict__ eidx,
    float* __restrict__ ws)
{
    const int tid = threadIdx.x;
    __shared__ float h[2048], x1[2048], part[4096], h2[512], x2[512];
    __shared__ float sxc[16];
    __shared__ float ss1[32], sd1[32], se1[96], al1[96], wt1[96], mx1[32], dn1[32];
    __shared__ float ss2[8], sd2[8], se2[24], al2[24], wt2[24], mx2[8], dn2[8];
    __shared__ int   esrc[24], edst[24];
    __shared__ float t2[160], y1[160], y2[16];
    __shared__ float sg1as[256], sg1ad[256], sg1ae[256], sg1b[256], sgl0[256], sgl1[256];
    __shared__ float sg2as[64], sg2ad[64], sg2ae[64], sg2b[64];

    // --- prefetch small weights (independent of everything) ---
    if (tid < 256) {
        sg1as[tid] = g1as[tid]; sg1ad[tid] = g1ad[tid];
        sg1ae[tid] = g1ae[tid]; sg1b[tid]  = g1b[tid];
        sgl0[tid] = g1lin[510 * 256 + tid]; sgl1[tid] = g1lin[511 * 256 + tid];
    } else if (tid < 320) {
        int c = tid - 256;
        sg2as[c] = g2as[c]; sg2ad[c] = g2ad[c]; sg2ae[c] = g2ae[c]; sg2b[c] = g2b[c];
    } else if (tid < 336)  { esrc[tid - 320] = eidx[tid - 320]; edst[tid - 320] = eidx[tid - 304]; }
    else if (tid < 344)    { esrc[tid - 320] = tid - 336;       edst[tid - 320] = tid - 336; }

    // --- CNN_1 (verified math) ---
    if (tid < 160) {
        int b_ = tid / 80, ch = (tid % 80) / 10, tt = tid % 10;
        int srow = ((ch & 1) == 0) ? 1 : 5;
        int n = 4 * b_ + (ch >> 1);
        t2[tid] = xft[srow * 80 + n * 10 + tt];
    }
    __syncthreads();
    if (tid < 160) {
        int b_ = tid / 80, co = (tid % 80) / 10, tt = tid % 10;
        float acc = c1b1[co];
        for (int ci = 0; ci < 8; ++ci)
            for (int k = 0; k < 3; ++k) {
                int p = tt + k - 1;
                if (p >= 0 && p < 10) acc += t2[b_ * 80 + ci * 10 + p] * c1w1[co * 24 + ci * 3 + k];
            }
        y1[tid] = fmaxf(acc, 0.f);
    }
    __syncthreads();
    if (tid < 16) {
        int b_ = tid >> 3, p = tid & 7;
        float acc = c1b2[0];
        for (int i = 0; i < 10; ++i)
            for (int k = 0; k < 3; ++k) {
                int q = p + k - 1;
                if (q >= 0 && q < 8) acc += y1[b_ * 80 + q * 10 + i] * c1w2[i * 3 + k];
            }
        y2[tid] = acc;
        sxc[tid] = fmaxf(y2[tid], 0.f);
    }
    __syncthreads();

    // --- h[n][j] = sum of 8 HX partials + CNN rows (g1_lin rows 510/511) ---
    {
        const int j = tid & 255, half = tid >> 8;
        for (int nl = 0; nl < 4; ++nl) {
            int n = half * 4 + nl;
            float acc = 0.f;
            #pragma unroll
            for (int cb = 0; cb < 8; ++cb) acc += ws[WS_HXPART + (cb * 8 + n) * 256 + j];
            acc += sxc[n * 2] * sgl0[j] + sxc[n * 2 + 1] * sgl1[j];
            h[n * 256 + j] = acc;
        }
    }
    __syncthreads();
    if (tid < 32) {                       // src/dst scores (4 heads)
        int n = tid >> 2, hd = tid & 3;
        float aS = 0.f, aD = 0.f;
        for (int c = 0; c < 64; ++c) {
            float hv = h[n * 256 + hd * 64 + c];
            aS += hv * sg1as[hd * 64 + c];
            aD += hv * sg1ad[hd * 64 + c];
        }
        ss1[tid] = aS; sd1[tid] = aD;
    } else if (tid < 128) {               // edge scores from ws HE1
        int idx = tid - 32;
        int e = idx >> 2, hd = idx & 3;
        float acc = 0.f;
        for (int c = 0; c < 64; ++c) acc += ws[WS_HE1 + e * 256 + hd * 64 + c] * sg1ae[hd * 64 + c];
        se1[idx] = acc;
    }
    __syncthreads();
    if (tid < 96) {
        int e = tid >> 2, hd = tid & 3;
        float s = ss1[esrc[e] * 4 + hd] + sd1[edst[e] * 4 + hd] + se1[tid];
        al1[tid] = (s > 0.f) ? s : 0.2f * s;
    }
    __syncthreads();
    if (tid < 32) {                       // scatter-softmax stats per (dst, head)
        int n = tid >> 2, hd = tid & 3;
        float mx = -1e30f;
        for (int e = 0; e < 24; ++e) if (edst[e] == n) mx = fmaxf(mx, al1[e * 4 + hd]);
        float dn = 0.f;
        for (int e = 0; e < 24; ++e) if (edst[e] == n) dn += expf(al1[e * 4 + hd] - mx);
        mx1[tid] = mx; dn1[tid] = dn;
    }
    __syncthreads();
    if (tid < 96) {
        int e = tid >> 2, hd = tid & 3, d = edst[e];
        wt1[tid] = expf(al1[tid] - mx1[d * 4 + hd]) / (dn1[d * 4 + hd] + 1e-16f);
    }
    __syncthreads();
    {   // aggregate + bias + relu -> x1
        const int j = tid & 255, half = tid >> 8, hd = j >> 6;
        for (int nl = 0; nl < 4; ++nl) {
            int n = half * 4 + nl;
            float acc = 0.f;
            for (int e = 0; e < 24; ++e)
                if (edst[e] == n) acc += wt1[e * 4 + hd] * h[esrc[e] * 256 + j];
            x1[n * 256 + j] = fmaxf(acc + sg1b[j], 0.f);
        }
    }
    __syncthreads();
    {   // h2 = x1 @ g2_lin — each g2lin element read from global exactly once
        const int c = tid & 63, kc = tid >> 6;    // one kc per wave
        float p[8];
        #pragma unroll
        for (int n = 0; n < 8; ++n) p[n] = 0.f;
        for (int kk = 0; kk < 32; ++kk) {
            int k = kc * 32 + kk;
            float g = g2lin[k * 64 + c];          // coalesced 256B/wave
            #pragma unroll
            for (int n = 0; n < 8; ++n) p[n] += x1[n * 256 + k] * g;
        }
        #pragma unroll
        for (int n = 0; n < 8; ++n) part[kc * 512 + n * 64 + c] = p[n];
    }
    __syncthreads();
    {   // reduce the 8 k-chunks
        const int n = tid >> 6, c = tid & 63;
        float acc = 0.f;
        #pragma unroll
        for (int kc = 0; kc < 8; ++kc) acc += part[kc * 512 + n * 64 + c];
        h2[n * 64 + c] = acc;
    }
    __syncthreads();
    if (tid < 8) {
        float aS = 0.f, aD = 0.f;
        for (int c = 0; c < 64; ++c) {
            float hv = h2[tid * 64 + c];
            aS += hv * sg2as[c]; aD += hv * sg2ad[c];
        }
        ss2[tid] = aS; sd2[tid] = aD;
    } else if (tid < 32) {
        int e = tid - 8;
        float acc = 0.f;
        for (int c = 0; c < 64; ++c) acc += ws[WS_HE2 + e * 64 + c] * sg2ae[c];
        se2[e] = acc;
    }
    __syncthreads();
    if (tid < 24) {
        float s = ss2[esrc[tid]] + sd2[edst[tid]] + se2[tid];
        al2[tid] = (s > 0.f) ? s : 0.2f * s;
    }
    __syncthreads();
    if (tid < 8) {
        float mx = -1e30f;
        for (int e = 0; e < 24; ++e) if (edst[e] == tid) mx = fmaxf(mx, al2[e]);
        float dn = 0.f;
        for (int e = 0; e < 24; ++e) if (edst[e] == tid) dn += expf(al2[e] - mx);
        mx2[tid] = mx; dn2[tid] = dn;
    }
    __syncthreads();
    if (tid < 24) {
        int d = edst[tid];
        wt2[tid] = expf(al2[tid] - mx2[d]) / (dn2[d] + 1e-16f);
    }
    __syncthreads();
    {
        const int n = tid >> 6, c = tid & 63;
        float acc = 0.f;
        for (int e = 0; e < 24; ++e)
            if (edst[e] == n) acc += wt2[e] * h2[esrc[e] * 64 + c];
        x2[n * 64 + c] = fmaxf(acc + sg2b[c], 0.f);
    }
    __syncthreads();
    if (tid < 64) {                      // x2 mean -> VM[0..63]
        float m = 0.f;
        for (int n = 0; n < 8; ++n) m += x2[n * 64 + tid];
        ws[WS_VM + tid] = m * 0.125f;
    }
}

// ========== K3: deconv (LDS-local) + CNN_2 + fused linear (16 blocks x 256) ===
__global__ __launch_bounds__(256) void k3_tail(
    const float* __restrict__ xft,
    const float* __restrict__ d1w, const float* __restrict__ d1b,
    const float* __restrict__ d2w, const float* __restrict__ d2b,
    const float* __restrict__ d3w, const float* __restrict__ d3b,
    const float* __restrict__ c2w1, const float* __restrict__ c2b1,
    const float* __restrict__ c2w2, const float* __restrict__ c2b2,
    const float* __restrict__ ws, float* __restrict__ out)
{
    const int tid = threadIdx.x;
    const int r0 = blockIdx.x * 4;
    __shared__ float smem[15964];
    float* sA   = smem;           // 7680: [3][64][4][10] deconv slice; later u/v/f
    float* sw2s = smem + 7680;    // 6144
    float* sw1s = smem + 13824;   // 384
    float* swfs = smem + 14208;   // 1280
    float* cins = smem + 15488;   // [4][4][10]
    float* vms  = smem + 15648;   // 192
    float* sb1  = smem + 15840;   // 32
    float* sb2  = smem + 15872;   // 64
    float* sbfs = smem + 15936;   // 16
    float* sdb  = smem + 15952;   // 12

    for (int idx = tid; idx < 7680; idx += 256) {
        int t = idx % 10, rl = (idx / 10) & 3, ii = idx / 40;
        int tau = ii >> 6, i = ii & 63;
        const float* dw = (tau == 0) ? d1w : (tau == 1) ? d2w : d3w;
        sA[idx] = dw[i * 640 + (r0 + rl) * 10 + t];
    }
    for (int idx = tid; idx < 6144; idx += 256) sw2s[idx] = c2w2[idx];
    for (int idx = tid; idx < 384; idx += 256) sw1s[idx] = c2w1[idx];
    for (int idx = tid; idx < 1280; idx += 256) swfs[idx] = ws[WS_WF + idx];
    if (tid < 32) sb1[tid] = c2b1[tid];
    if (tid < 64) sb2[tid] = c2b2[tid];
    if (tid < 40) { int rl = tid / 10, t = tid % 10; cins[rl * 40 + 10 + t] = xft[(r0 + rl) * 10 + t]; }
    if (tid < 12) {
        int tau = tid / 4, rl = tid % 4;
        const float* db = (tau == 0) ? d1b : (tau == 1) ? d2b : d3b;
        sdb[tid] = db[r0 + rl];
    }
    if (tid >= 40 && tid < 232) vms[tid - 40] = ws[WS_VM + tid - 40];
    if (tid < 10)  sbfs[tid] = ws[WS_BF + tid];
    __syncthreads();

    if (tid < 120) {                          // deconv: 4 rl x 3 tau x 10 t
        int t = tid % 10, tau = (tid / 10) % 3, rl = tid / 30;
        float acc = sdb[tau * 4 + rl];
        for (int i = 0; i < 64; ++i)
            acc += vms[tau * 64 + i] * sA[((tau * 64 + i) * 4 + rl) * 10 + t];
        int ch = (tau == 0) ? 0 : (tau + 1);  // tau0->ch0(x_pool), tau1->ch2(ef), tau2->ch3(er)
        cins[rl * 40 + ch * 10 + t] = acc;
    }
    __syncthreads();
    float* u = sA; float* v = sA + 2048; float* f = sA + 3072;  // alias dead sA
    for (int o = tid; o < 1024; o += 256) {   // conv1, pad 0
        int rl = o >> 8, co = (o >> 3) & 31, p = o & 7;
        float acc = sb1[co];
        #pragma unroll
        for (int ci = 0; ci < 4; ++ci)
            #pragma unroll
            for (int k = 0; k < 3; ++k)
                acc += cins[rl * 40 + ci * 10 + p + k] * sw1s[co * 12 + ci * 3 + k];
        u[o] = acc;
    }
    __syncthreads();
    for (int o = tid; o < 512; o += 256) {    // maxpool(2)
        int rl = o >> 7, co = (o >> 2) & 31, q = o & 3;
        v[o] = fmaxf(u[rl * 256 + co * 8 + 2 * q], u[rl * 256 + co * 8 + 2 * q + 1]);
    }
    __syncthreads();
    for (int o = tid; o < 512; o += 256) {    // conv2 + flatten
        int rl = o >> 7, m = o & 127, co2 = m >> 1, p = m & 1;
        float acc = sb2[co2];
        for (int ci = 0; ci < 32; ++ci)
            #pragma unroll
            for (int k = 0; k < 3; ++k)
                acc += v[rl * 128 + ci * 4 + p + k] * sw2s[co2 * 96 + ci * 3 + k];
        f[rl * 128 + m] = acc;
    }
    __syncthreads();
    if (tid < 40) {                           // fused (l1->l2) + relu -> out
        int rl = tid / 10, t = tid % 10;
        float acc = sbfs[t];
        for (int m = 0; m < 128; ++m) acc += f[rl * 128 + m] * swfs[m * 10 + t];
        out[(r0 + rl) * 10 + t] = fmaxf(acc, 0.f);
    }
}

extern "C" void kernel_launch(void* const* d_in, const int* in_sizes, int n_in,
                              void* d_out, int out_size, void* d_ws, size_t ws_size,
                              hipStream_t stream)
{
    const float* xf    = (const float*)d_in[0];
    const float* xft   = (const float*)d_in[1];
    const float* ea    = (const float*)d_in[2];
    const float* c1w1  = (const float*)d_in[3];
    const float* c1b1  = (const float*)d_in[4];
    const float* c1w2  = (const float*)d_in[5];
    const float* c1b2  = (const float*)d_in[6];
    const float* g1lin = (const float*)d_in[7];
    const float* g1as  = (const float*)d_in[8];
    const float* g1ad  = (const float*)d_in[9];
    const float* g1le  = (const float*)d_in[10];
    const float* g1ae  = (const float*)d_in[11];
    const float* g1b   = (const float*)d_in[12];
    const float* g2lin = (const float*)d_in[13];
    const float* g2as  = (const float*)d_in[14];
    const float* g2ad  = (const float*)d_in[15];
    const float* g2le  = (const float*)d_in[16];
    const float* g2ae  = (const float*)d_in[17];
    const float* g2b   = (const float*)d_in[18];
    const float* mw1   = (const float*)d_in[19];
    const float* mb1   = (const float*)d_in[20];
    const float* mw2   = (const float*)d_in[21];
    const float* mb2   = (const float*)d_in[22];
    const float* d1w   = (const float*)d_in[23];
    const float* d1b   = (const float*)d_in[24];
    const float* d2w   = (const float*)d_in[25];
    const float* d2b   = (const float*)d_in[26];
    const float* d3w   = (const float*)d_in[27];
    const float* d3b   = (const float*)d_in[28];
    const float* c2w1  = (const float*)d_in[29];
    const float* c2b1  = (const float*)d_in[30];
    const float* c2w2  = (const float*)d_in[31];
    const float* c2b2  = (const float*)d_in[32];
    const float* l1w   = (const float*)d_in[33];
    const float* l1b   = (const float*)d_in[34];
    const float* l2w   = (const float*)d_in[35];
    const float* l2b   = (const float*)d_in[36];
    const int*   eidx  = (const int*)d_in[37];
    float* ws  = (float*)d_ws;
    float* out = (float*)d_out;

    hipLaunchKernelGGL(k1_pre, dim3(17), dim3(256), 0, stream,
        xf, ea, g1lin, g1le, mw1, mb1, mw2, mb2, g2le, l1w, l1b, l2w, l2b, ws);
    hipLaunchKernelGGL(k2_gat, dim3(1), dim3(512), 0, stream,
        xft, c1w1, c1b1, c1w2, c1b2,
        g1lin, g1as, g1ad, g1ae, g1b,
        g2lin, g2as, g2ad, g2ae, g2b, eidx, ws);
    hipLaunchKernelGGL(k3_tail, dim3(16), dim3(256), 0, stream,
        xft, d1w, d1b, d2w, d2b, d3w, d3b,
        c2w1, c2b1, c2w2, c2b2, ws, out);
}

// Round 5
// 43.745 us; speedup vs baseline: 1.6015x; 1.3198x over previous
//
#include <hip/hip_runtime.h>
#include <math.h>

// ---------------- workspace layout (float offsets) ----------------
#define WS_HXPART 0          // [8 chunk][8 n][256 j] partials of x@g1_lin[:510]
#define WS_XCNN   16384      // [16] CNN_1 output
#define WS_SE1    16400      // [68]: 16 edges x 4 heads + 4 self-loop heads
#define WS_SE2    16468      // [17]: 16 edges + 1 self-loop
#define WS_WF     16512      // [128][10] fused c2l1w@c2l2w
#define WS_BF     17792      // [10]
#define WS_VM     17808      // [3][64]; only [64..192) (ea_new even/odd means) used

// ================= K1: parallel precompute (15 blocks x 256) =================
__global__ __launch_bounds__(256) void k1_pre(
    const float* __restrict__ xf,   const float* __restrict__ xft,
    const float* __restrict__ ea,
    const float* __restrict__ c1w1, const float* __restrict__ c1b1,
    const float* __restrict__ c1w2, const float* __restrict__ c1b2,
    const float* __restrict__ g1lin,const float* __restrict__ g1le,
    const float* __restrict__ g1ae,
    const float* __restrict__ mw1,  const float* __restrict__ mb1,
    const float* __restrict__ mw2,  const float* __restrict__ mb2,
    const float* __restrict__ g2le, const float* __restrict__ g2ae,
    const float* __restrict__ l1w,  const float* __restrict__ l1b,
    const float* __restrict__ l2w,  const float* __restrict__ l2b,
    float* __restrict__ ws)
{
    const int b = blockIdx.x, tid = threadIdx.x;
    if (b < 8) {
        // ---------- HX partials: chunk b of x_feat @ g1_lin[:510] ----------
        __shared__ float sx[512];             // [8][64]
        const int k0 = b * 64;
        const int klen = (b == 7) ? 62 : 64;
        for (int idx = tid; idx < 512; idx += 256) {
            int n = idx >> 6, kk = idx & 63;
            sx[n * 64 + kk] = (kk < klen) ? xf[n * 510 + k0 + kk] : 0.f;
        }
        __syncthreads();
        float acc[8];
        #pragma unroll
        for (int n = 0; n < 8; ++n) acc[n] = 0.f;
        for (int kk = 0; kk < 64; ++kk) {
            float w = g1lin[(k0 + kk) * 256 + tid];
            #pragma unroll
            for (int n = 0; n < 8; ++n) acc[n] += sx[n * 64 + kk] * w;
        }
        #pragma unroll
        for (int n = 0; n < 8; ++n) ws[WS_HXPART + (b * 8 + n) * 256 + tid] = acc[n];
    } else if (b == 8) {
        // ---------- fold q1 = g1le @ a_e ; se1 = ea_ext @ q1 ----------
        __shared__ float sea[2048 + 128];     // edge_attr + mean row
        __shared__ float sae[256], q1[512];
        for (int idx = tid; idx < 2048; idx += 256) sea[idx] = ea[idx];
        sae[tid] = g1ae[tid];
        __syncthreads();
        if (tid < 128) {
            float m = 0.f;
            for (int e = 0; e < 16; ++e) m += sea[e * 128 + tid];
            sea[2048 + tid] = m * (1.f / 16.f);
        }
        __syncthreads();
        for (int o = tid; o < 512; o += 256) {
            int k = o >> 2, hd = o & 3;
            float acc = 0.f;
            for (int c = 0; c < 64; ++c) acc += g1le[k * 256 + hd * 64 + c] * sae[hd * 64 + c];
            q1[o] = acc;
        }
        __syncthreads();
        if (tid < 64) {                       // real edges
            int e = tid >> 2, hd = tid & 3;
            float acc = 0.f;
            for (int k = 0; k < 128; ++k) acc += sea[e * 128 + k] * q1[k * 4 + hd];
            ws[WS_SE1 + tid] = acc;
        } else if (tid < 68) {                // self-loop (shared mean row)
            int hd = tid - 64;
            float acc = 0.f;
            for (int k = 0; k < 128; ++k) acc += sea[2048 + k] * q1[k * 4 + hd];
            ws[WS_SE1 + 64 + hd] = acc;
        }
    } else if (b == 9) {
        // ---------- edge MLP -> ea_new ; even/odd means ; q2-fold ; se2 ----------
        __shared__ float sea[2048];
        __shared__ float tmp[1024];
        __shared__ float ean[17 * 64];
        __shared__ float sq2a[64], sq2[64];
        for (int idx = tid; idx < 2048; idx += 256) sea[idx] = ea[idx];
        if (tid < 64) sq2a[tid] = g2ae[tid];
        __syncthreads();
        for (int o = tid; o < 1024; o += 256) {
            int e = o >> 6, c = o & 63;
            float acc = mb1[c];
            for (int k = 0; k < 128; ++k) acc += sea[e * 128 + k] * mw1[k * 64 + c];
            tmp[o] = fmaxf(acc, 0.f);
        }
        __syncthreads();
        for (int o = tid; o < 1024; o += 256) {
            int e = o >> 6, c = o & 63;
            float acc = mb2[c];
            for (int k = 0; k < 64; ++k) acc += tmp[e * 64 + k] * mw2[k * 64 + c];
            ean[o] = acc;
        }
        __syncthreads();
        if (tid < 64) {                           // self-loop fill row (mean of 16)
            float m = 0.f;
            for (int e = 0; e < 16; ++e) m += ean[e * 64 + tid];
            ean[1024 + tid] = m * (1.f / 16.f);
        } else if (tid < 128) {                   // even mean -> VM[64..127]
            int c = tid - 64;
            float m = 0.f;
            for (int e = 0; e < 16; e += 2) m += ean[e * 64 + c];
            ws[WS_VM + 64 + c] = m * 0.125f;
        } else if (tid < 192) {                   // odd mean -> VM[128..191]
            int c = tid - 128;
            float m = 0.f;
            for (int e = 1; e < 16; e += 2) m += ean[e * 64 + c];
            ws[WS_VM + 128 + c] = m * 0.125f;
        }
        __syncthreads();
        if (tid < 64) {                           // q2[k] = g2le[k,:] . g2ae
            float acc = 0.f;
            for (int c = 0; c < 64; ++c) acc += g2le[tid * 64 + c] * sq2a[c];
            sq2[tid] = acc;
        }
        __syncthreads();
        if (tid < 16) {
            float acc = 0.f;
            for (int k = 0; k < 64; ++k) acc += ean[tid * 64 + k] * sq2[k];
            ws[WS_SE2 + tid] = acc;
        } else if (tid == 16) {
            float acc = 0.f;
            for (int k = 0; k < 64; ++k) acc += ean[1024 + k] * sq2[k];
            ws[WS_SE2 + 16] = acc;
        }
    } else if (b == 10) {
        // ---------- CNN_1 (verified) ----------
        __shared__ float t2[160], y1[160], y2[16];
        if (tid < 160) {
            int b_ = tid / 80, ch = (tid % 80) / 10, tt = tid % 10;
            int srow = ((ch & 1) == 0) ? 1 : 5;
            int n = 4 * b_ + (ch >> 1);
            t2[tid] = xft[srow * 80 + n * 10 + tt];
        }
        __syncthreads();
        if (tid < 160) {
            int b_ = tid / 80, co = (tid % 80) / 10, tt = tid % 10;
            float acc = c1b1[co];
            for (int ci = 0; ci < 8; ++ci)
                for (int k = 0; k < 3; ++k) {
                    int p = tt + k - 1;
                    if (p >= 0 && p < 10) acc += t2[b_ * 80 + ci * 10 + p] * c1w1[co * 24 + ci * 3 + k];
                }
            y1[tid] = fmaxf(acc, 0.f);
        }
        __syncthreads();
        if (tid < 16) {
            int b_ = tid >> 3, p = tid & 7;
            float acc = c1b2[0];
            for (int i = 0; i < 10; ++i)
                for (int k = 0; k < 3; ++k) {
                    int q = p + k - 1;
                    if (q >= 0 && q < 8) acc += y1[b_ * 80 + q * 10 + i] * c1w2[i * 3 + k];
                }
            y2[tid] = acc;
        }
        __syncthreads();
        if (tid < 16) ws[WS_XCNN + tid] = fmaxf(y2[tid], 0.f);
    } else {
        // ---------- fused tail linear: wf = c2l1w @ c2l2w (+ bf on b11) ----------
        __shared__ float sl2[2560];
        for (int idx = tid; idx < 2560; idx += 256) sl2[idx] = l2w[idx];
        __syncthreads();
        const int m0 = (b - 11) * 32;
        for (int o = tid; o < 320; o += 256) {
            int ml = o / 10, t = o % 10, m = m0 + ml;
            float acc = 0.f;
            for (int j = 0; j < 256; ++j) acc += l1w[m * 256 + j] * sl2[j * 10 + t];
            ws[WS_WF + m * 10 + t] = acc;
        }
        if (b == 11 && tid < 10) {
            float acc = l2b[tid];
            for (int j = 0; j < 256; ++j) acc += l1b[j] * sl2[j * 10 + tid];
            ws[WS_BF + tid] = acc;
        }
    }
}

// ======== K2: redundant GAT chain + per-block tail (16 blocks x 512) =========
// LDS map (floats) -- front regions die before the tail reuses them
#define P_H2P  0      // 2048 h2 partials          | tail sA[0:2048)
#define P_SH   2048   // 2048 h                    | tail sA
#define P_SX1  4096   // 2048 x1                   | tail sA
#define P_SGL0 6144   // 256
#define P_SGL1 6400   // 256
#define P_SH2  6656   // 512
#define P_SX2  7168   // 512                       | tail sA ends 7680
#define P_SE1F 7680   // 96                        | tail sw2 starts 7680
#define P_SE2F 7776   // 24
#define P_ESRC 7800   // 24 (int)
#define P_EDST 7824   // 24 (int)
#define P_SXC  7848   // 16
#define P_SS1  7864   // 32
#define P_SD1  7896   // 32
#define P_AL1  7928   // 96
#define P_WT1  8024   // 96
#define P_MX1  8120   // 32
#define P_DN1  8152   // 32
#define P_SS2  8184   // 8
#define P_SD2  8192   // 8
#define P_AL2  8200   // 24
#define P_WT2  8224   // 24
#define P_MX2  8248   // 8
#define P_DN2  8256   // 8
#define P_G1AS 8320   // 256
#define P_G1AD 8576   // 256
#define P_G1B  8832   // 256
#define P_G2AS 9088   // 64
#define P_G2AD 9152   // 64
#define P_G2B  9216   // 64  (front ends 9280)
// tail-only regions
#define P_SA   0      // 7680 deconv slices; after deconv: u[0:1024) v[1024:1536) f[1536:2048)
#define P_SW2  7680   // 6144
#define P_CIN  13824  // 160
#define P_SW1  13984  // 384
#define P_SB1  14368  // 32
#define P_SB2  14400  // 64
#define P_SDB  14464  // 12
#define P_SBF  14480  // 16
#define P_SWF  14496  // 1280 (loaded at S0; region untouched by front)
#define P_SVM  15776  // 192  (vm0 written S4; vmE loaded S0)

__global__ __launch_bounds__(512) void k2_main(
    const float* __restrict__ xft,
    const float* __restrict__ g1lin,
    const float* __restrict__ g1as, const float* __restrict__ g1ad,
    const float* __restrict__ g1b,
    const float* __restrict__ g2lin,
    const float* __restrict__ g2as, const float* __restrict__ g2ad,
    const float* __restrict__ g2b,
    const int* __restrict__ eidx,
    const float* __restrict__ d1w, const float* __restrict__ d1b,
    const float* __restrict__ d2w, const float* __restrict__ d2b,
    const float* __restrict__ d3w, const float* __restrict__ d3b,
    const float* __restrict__ c2w1, const float* __restrict__ c2b1,
    const float* __restrict__ c2w2, const float* __restrict__ c2b2,
    const float* __restrict__ ws, float* __restrict__ out)
{
    __shared__ float sm[16000];
    const int tid = threadIdx.x;
    const int r0 = blockIdx.x * 4;
    int* esrc = (int*)sm + P_ESRC;
    int* edst = (int*)sm + P_EDST;

    // ---------------- S0: coalesced staging of all small operands ----------------
    if (tid < 96) { int e = tid >> 2; sm[P_SE1F + tid] = (e < 16) ? ws[WS_SE1 + tid] : ws[WS_SE1 + 64 + (tid & 3)]; }
    else if (tid < 120) { int e = tid - 96; sm[P_SE2F + e] = (e < 16) ? ws[WS_SE2 + e] : ws[WS_SE2 + 16]; }
    else if (tid < 136) sm[P_SXC + tid - 120] = ws[WS_XCNN + tid - 120];
    else if (tid < 160) {
        int i = tid - 136;
        esrc[i] = (i < 16) ? eidx[i]      : i - 16;
        edst[i] = (i < 16) ? eidx[16 + i] : i - 16;
    }
    else if (tid < 288) sm[P_SVM + 64 + (tid - 160)] = ws[WS_VM + 64 + (tid - 160)];  // vmE
    else if (tid < 298) sm[P_SBF + tid - 288] = ws[WS_BF + tid - 288];
    else if (tid < 310) {
        int i = tid - 298, tau = i / 4, rl = i % 4;
        const float* db = (tau == 0) ? d1b : (tau == 1) ? d2b : d3b;
        sm[P_SDB + i] = db[r0 + rl];
    }
    else if (tid < 342) sm[P_SB1 + tid - 310] = c2b1[tid - 310];
    else if (tid < 406) sm[P_SB2 + tid - 342] = c2b2[tid - 342];
    else if (tid < 446) { int i = tid - 406, rl = i / 10, t = i % 10; sm[P_CIN + rl * 40 + 10 + t] = xft[(r0 + rl) * 10 + t]; }
    if (tid < 256) {
        sm[P_SGL0 + tid] = g1lin[510 * 256 + tid];
        sm[P_G1AS + tid] = g1as[tid];
        sm[P_G1AD + tid] = g1ad[tid];
        sm[P_G1B  + tid] = g1b[tid];
    } else {
        int j = tid - 256;
        sm[P_SGL1 + j] = g1lin[511 * 256 + j];
        if (j < 64) { sm[P_G2AS + j] = g2as[j]; sm[P_G2AD + j] = g2ad[j]; sm[P_G2B + j] = g2b[j]; }
    }
    for (int idx = tid; idx < 1280; idx += 512) sm[P_SWF + idx] = ws[WS_WF + idx];
    for (int idx = tid; idx < 384;  idx += 512) sm[P_SW1 + idx] = c2w1[idx];
    __syncthreads();

    // ---------------- S1: h = sum of partials + CNN columns ----------------
    {
        const int j = tid & 255, half = tid >> 8;
        for (int nl = 0; nl < 4; ++nl) {
            int n = half * 4 + nl;
            float acc = 0.f;
            #pragma unroll
            for (int cb = 0; cb < 8; ++cb) acc += ws[WS_HXPART + (cb * 8 + n) * 256 + j];
            acc += sm[P_SXC + n * 2] * sm[P_SGL0 + j] + sm[P_SXC + n * 2 + 1] * sm[P_SGL1 + j];
            sm[P_SH + n * 256 + j] = acc;
        }
    }
    __syncthreads();
    // ---------------- S2: GAT1 (all operands in LDS) ----------------
    if (tid < 32) {
        int n = tid >> 2, hd = tid & 3;
        float aS = 0.f, aD = 0.f;
        for (int c = 0; c < 64; ++c) {
            float hv = sm[P_SH + n * 256 + hd * 64 + c];
            aS += hv * sm[P_G1AS + hd * 64 + c];
            aD += hv * sm[P_G1AD + hd * 64 + c];
        }
        sm[P_SS1 + tid] = aS; sm[P_SD1 + tid] = aD;
    }
    __syncthreads();
    if (tid < 96) {
        int e = tid >> 2, hd = tid & 3;
        float s = sm[P_SS1 + esrc[e] * 4 + hd] + sm[P_SD1 + edst[e] * 4 + hd] + sm[P_SE1F + tid];
        sm[P_AL1 + tid] = (s > 0.f) ? s : 0.2f * s;
    }
    __syncthreads();
    if (tid < 32) {
        int n = tid >> 2, hd = tid & 3;
        float mx = -1e30f;
        for (int e = 0; e < 24; ++e) if (edst[e] == n) mx = fmaxf(mx, sm[P_AL1 + e * 4 + hd]);
        float dn = 0.f;
        for (int e = 0; e < 24; ++e) if (edst[e] == n) dn += expf(sm[P_AL1 + e * 4 + hd] - mx);
        sm[P_MX1 + tid] = mx; sm[P_DN1 + tid] = dn;
    }
    __syncthreads();
    if (tid < 96) {
        int e = tid >> 2, hd = tid & 3, d = edst[e];
        sm[P_WT1 + tid] = expf(sm[P_AL1 + tid] - sm[P_MX1 + d * 4 + hd]) / (sm[P_DN1 + d * 4 + hd] + 1e-16f);
    }
    __syncthreads();
    {   // aggregate + bias + relu -> x1
        const int j = tid & 255, half = tid >> 8, hd = j >> 6;
        for (int nl = 0; nl < 4; ++nl) {
            int n = half * 4 + nl;
            float acc = 0.f;
            for (int e = 0; e < 24; ++e)
                if (edst[e] == n) acc += sm[P_WT1 + e * 4 + hd] * sm[P_SH + esrc[e] * 256 + j];
            sm[P_SX1 + n * 256 + j] = fmaxf(acc + sm[P_G1B + j], 0.f);
        }
    }
    __syncthreads();
    // ---------------- S3: h2 = x1 @ g2_lin (4-way k-split) ----------------
    {
        const int kc = tid >> 7, sub = (tid >> 6) & 1, c = tid & 63;
        float p0 = 0.f, p1 = 0.f, p2 = 0.f, p3 = 0.f;
        for (int kk = 0; kk < 64; ++kk) {
            int k = kc * 64 + kk;
            float g = g2lin[k * 64 + c];
            p0 += sm[P_SX1 + (sub * 4 + 0) * 256 + k] * g;
            p1 += sm[P_SX1 + (sub * 4 + 1) * 256 + k] * g;
            p2 += sm[P_SX1 + (sub * 4 + 2) * 256 + k] * g;
            p3 += sm[P_SX1 + (sub * 4 + 3) * 256 + k] * g;
        }
        sm[P_H2P + kc * 512 + (sub * 4 + 0) * 64 + c] = p0;
        sm[P_H2P + kc * 512 + (sub * 4 + 1) * 64 + c] = p1;
        sm[P_H2P + kc * 512 + (sub * 4 + 2) * 64 + c] = p2;
        sm[P_H2P + kc * 512 + (sub * 4 + 3) * 64 + c] = p3;
    }
    __syncthreads();
    sm[P_SH2 + tid] = sm[P_H2P + tid] + sm[P_H2P + 512 + tid] + sm[P_H2P + 1024 + tid] + sm[P_H2P + 1536 + tid];
    __syncthreads();
    // ---------------- S4: GAT2 + x2 + vm0 ----------------
    if (tid < 8) {
        float aS = 0.f, aD = 0.f;
        for (int c = 0; c < 64; ++c) {
            float hv = sm[P_SH2 + tid * 64 + c];
            aS += hv * sm[P_G2AS + c]; aD += hv * sm[P_G2AD + c];
        }
        sm[P_SS2 + tid] = aS; sm[P_SD2 + tid] = aD;
    }
    __syncthreads();
    if (tid < 24) {
        float s = sm[P_SS2 + esrc[tid]] + sm[P_SD2 + edst[tid]] + sm[P_SE2F + tid];
        sm[P_AL2 + tid] = (s > 0.f) ? s : 0.2f * s;
    }
    __syncthreads();
    if (tid < 8) {
        float mx = -1e30f;
        for (int e = 0; e < 24; ++e) if (edst[e] == tid) mx = fmaxf(mx, sm[P_AL2 + e]);
        float dn = 0.f;
        for (int e = 0; e < 24; ++e) if (edst[e] == tid) dn += expf(sm[P_AL2 + e] - mx);
        sm[P_MX2 + tid] = mx; sm[P_DN2 + tid] = dn;
    }
    __syncthreads();
    if (tid < 24) {
        int d = edst[tid];
        sm[P_WT2 + tid] = expf(sm[P_AL2 + tid] - sm[P_MX2 + d]) / (sm[P_DN2 + d] + 1e-16f);
    }
    __syncthreads();
    {
        const int n = tid >> 6, c = tid & 63;
        float acc = 0.f;
        for (int e = 0; e < 24; ++e)
            if (edst[e] == n) acc += sm[P_WT2 + e] * sm[P_SH2 + esrc[e] * 64 + c];
        sm[P_SX2 + n * 64 + c] = fmaxf(acc + sm[P_G2B + c], 0.f);
    }
    __syncthreads();
    if (tid < 64) {
        float m = 0.f;
        for (int n = 0; n < 8; ++n) m += sm[P_SX2 + n * 64 + tid];
        sm[P_SVM + tid] = m * 0.125f;
    }
    __syncthreads();   // front dead; SVM complete

    // ---------------- TAIL: deconv + CNN_2 + fused linear ----------------
    for (int idx = tid; idx < 7680; idx += 512) {
        int t = idx % 10, rl = (idx / 10) & 3, ii = idx / 40;
        int tau = ii >> 6, i = ii & 63;
        const float* dw = (tau == 0) ? d1w : (tau == 1) ? d2w : d3w;
        sm[P_SA + idx] = dw[i * 640 + (r0 + rl) * 10 + t];
    }
    for (int idx = tid; idx < 6144; idx += 512) sm[P_SW2 + idx] = c2w2[idx];
    __syncthreads();
    if (tid < 120) {                          // deconv: 4 rl x 3 tau x 10 t
        int t = tid % 10, tau = (tid / 10) % 3, rl = tid / 30;
        float acc = sm[P_SDB + tau * 4 + rl];
        for (int i = 0; i < 64; ++i)
            acc += sm[P_SVM + tau * 64 + i] * sm[P_SA + ((tau * 64 + i) * 4 + rl) * 10 + t];
        int ch = (tau == 0) ? 0 : (tau + 1);
        sm[P_CIN + rl * 40 + ch * 10 + t] = acc;
    }
    __syncthreads();
    for (int o = tid; o < 1024; o += 512) {   // conv1, pad 0 (u = sA[0:1024))
        int rl = o >> 8, co = (o >> 3) & 31, p = o & 7;
        float acc = sm[P_SB1 + co];
        #pragma unroll
        for (int ci = 0; ci < 4; ++ci)
            #pragma unroll
            for (int k = 0; k < 3; ++k)
                acc += sm[P_CIN + rl * 40 + ci * 10 + p + k] * sm[P_SW1 + co * 12 + ci * 3 + k];
        sm[P_SA + o] = acc;
    }
    __syncthreads();
    for (int o = tid; o < 512; o += 512) {    // maxpool(2) (v = sA[1024:1536))
        int rl = o >> 7, co = (o >> 2) & 31, q = o & 3;
        sm[P_SA + 1024 + o] = fmaxf(sm[P_SA + rl * 256 + co * 8 + 2 * q],
                                    sm[P_SA + rl * 256 + co * 8 + 2 * q + 1]);
    }
    __syncthreads();
    for (int o = tid; o < 512; o += 512) {    // conv2 + flatten (f = sA[1536:2048))
        int rl = o >> 7, m = o & 127, co2 = m >> 1, p = m & 1;
        float acc = sm[P_SB2 + co2];
        for (int ci = 0; ci < 32; ++ci)
            #pragma unroll
            for (int k = 0; k < 3; ++k)
                acc += sm[P_SA + 1024 + rl * 128 + ci * 4 + p + k] * sm[P_SW2 + co2 * 96 + ci * 3 + k];
        sm[P_SA + 1536 + o] = acc;
    }
    __syncthreads();
    if (tid < 40) {                           // fused (l1->l2) + relu -> out
        int rl = tid / 10, t = tid % 10;
        float acc = sm[P_SBF + t];
        for (int m = 0; m < 128; ++m) acc += sm[P_SA + 1536 + rl * 128 + m] * sm[P_SWF + m * 10 + t];
        out[(r0 + rl) * 10 + t] = fmaxf(acc, 0.f);
    }
}

extern "C" void kernel_launch(void* const* d_in, const int* in_sizes, int n_in,
                              void* d_out, int out_size, void* d_ws, size_t ws_size,
                              hipStream_t stream)
{
    const float* xf    = (const float*)d_in[0];
    const float* xft   = (const float*)d_in[1];
    const float* ea    = (const float*)d_in[2];
    const float* c1w1  = (const float*)d_in[3];
    const float* c1b1  = (const float*)d_in[4];
    const float* c1w2  = (const float*)d_in[5];
    const float* c1b2  = (const float*)d_in[6];
    const float* g1lin = (const float*)d_in[7];
    const float* g1as  = (const float*)d_in[8];
    const float* g1ad  = (const float*)d_in[9];
    const float* g1le  = (const float*)d_in[10];
    const float* g1ae  = (const float*)d_in[11];
    const float* g1b   = (const float*)d_in[12];
    const float* g2lin = (const float*)d_in[13];
    const float* g2as  = (const float*)d_in[14];
    const float* g2ad  = (const float*)d_in[15];
    const float* g2le  = (const float*)d_in[16];
    const float* g2ae  = (const float*)d_in[17];
    const float* g2b   = (const float*)d_in[18];
    const float* mw1   = (const float*)d_in[19];
    const float* mb1   = (const float*)d_in[20];
    const float* mw2   = (const float*)d_in[21];
    const float* mb2   = (const float*)d_in[22];
    const float* d1w   = (const float*)d_in[23];
    const float* d1b   = (const float*)d_in[24];
    const float* d2w   = (const float*)d_in[25];
    const float* d2b   = (const float*)d_in[26];
    const float* d3w   = (const float*)d_in[27];
    const float* d3b   = (const float*)d_in[28];
    const float* c2w1  = (const float*)d_in[29];
    const float* c2b1  = (const float*)d_in[30];
    const float* c2w2  = (const float*)d_in[31];
    const float* c2b2  = (const float*)d_in[32];
    const float* l1w   = (const float*)d_in[33];
    const float* l1b   = (const float*)d_in[34];
    const float* l2w   = (const float*)d_in[35];
    const float* l2b   = (const float*)d_in[36];
    const int*   eidx  = (const int*)d_in[37];
    float* ws  = (float*)d_ws;
    float* out = (float*)d_out;

    hipLaunchKernelGGL(k1_pre, dim3(15), dim3(256), 0, stream,
        xf, xft, ea, c1w1, c1b1, c1w2, c1b2,
        g1lin, g1le, g1ae, mw1, mb1, mw2, mb2,
        g2le, g2ae, l1w, l1b, l2w, l2b, ws);
    hipLaunchKernelGGL(k2_main, dim3(16), dim3(512), 0, stream,
        xft, g1lin, g1as, g1ad, g1b,
        g2lin, g2as, g2ad, g2b, eidx,
        d1w, d1b, d2w, d2b, d3w, d3b,
        c2w1, c2b1, c2w2, c2b2, ws, out);
}

// Round 6
// 33.128 us; speedup vs baseline: 2.1147x; 1.3205x over previous
//
#include <hip/hip_runtime.h>
#include <math.h>

// ---------------- workspace layout (float offsets) ----------------
#define WS_HXPART 0          // [8 chunk][8 n][256 j] partials of x@g1_lin[:510]
#define WS_SMALL  16384      // contiguous small block, mirrored to LDS by k2
#define WS_XCNN   16384      // +0    [16]
#define WS_SE1    16400      // +16   [68]  e*4+hd (e<16), self-loop at +64+hd
#define WS_SE2    16468      // +84   [17]
#define WS_WF     16488      // +104  [128*10]
#define WS_BF     17768      // +1384 [10]
#define WS_VM     17778      // +1394 [192]; k1 writes [64..192) (ea_new means)

// ---------------- k2 LDS map (floats); total 16124 -> sm[16128] --------------
// front (dies before tail):
#define F_H    0      // 2048
#define F_X1   2048   // 2048
#define F_H2P  4096   // 2048
#define F_H2   6144   // 512
#define F_X2   6656   // 512
#define F_G1AS 7168   // 256
#define F_G1AD 7424   // 256
#define F_G1B  7680   // 256
#define F_GL0  7936   // 256
#define F_GL1  8192   // 256
#define F_G2AS 8448   // 64
#define F_G2AD 8512   // 64
#define F_G2B  8576   // 64
#define F_SS1  8704   // 32
#define F_SD1  8736   // 32
#define F_AL1  8768   // 96
#define F_WT1  8864   // 96
#define F_MX1  8960   // 32
#define F_DN1  8992   // 32
#define F_A1   9024   // 256  [s*32 + n*4 + hd]
#define F_SS2  9280   // 8
#define F_SD2  9288   // 8
#define F_AL2  9296   // 24
#define F_WT2  9320   // 24
#define F_MX2  9344   // 8
#define F_DN2  9352   // 8
#define F_A2   9360   // 64   [n*8 + s]
// tail (overlays all of the above after x2/vm0):
#define F_SA   0      // 7680 deconv slices; then u@0(1024) v@1024(512) f@1536(512)
#define F_SW2  7680   // 6144
// persistent:
#define F_SML  13824  // 1600 (ws small mirror)
#define SM_XCNN 0
#define SM_SE1  16
#define SM_SE2  84
#define SM_WF   104
#define SM_BF   1384
#define SM_VM   1394
#define F_SW1  15424  // 384
#define F_CIN  15808  // 160
#define F_ESRC 15968  // 24 (int)
#define F_EDST 15992  // 24 (int)
#define F_SB1  16016  // 32
#define F_SB2  16048  // 64
#define F_SDB  16112  // 12

// ================= K1: parallel precompute (15 blocks x 256) =================
__global__ __launch_bounds__(256) void k1_pre(
    const float* __restrict__ xf,   const float* __restrict__ xft,
    const float* __restrict__ ea,
    const float* __restrict__ c1w1, const float* __restrict__ c1b1,
    const float* __restrict__ c1w2, const float* __restrict__ c1b2,
    const float* __restrict__ g1lin,const float* __restrict__ g1le,
    const float* __restrict__ g1ae,
    const float* __restrict__ mw1,  const float* __restrict__ mb1,
    const float* __restrict__ mw2,  const float* __restrict__ mb2,
    const float* __restrict__ g2le, const float* __restrict__ g2ae,
    const float* __restrict__ l1w,  const float* __restrict__ l1b,
    const float* __restrict__ l2w,  const float* __restrict__ l2b,
    float* __restrict__ ws)
{
    const int b = blockIdx.x, tid = threadIdx.x;
    if (b < 8) {
        __shared__ float sx[512];             // [8][64]
        const int k0 = b * 64;
        const int klen = (b == 7) ? 62 : 64;
        for (int idx = tid; idx < 512; idx += 256) {
            int n = idx >> 6, kk = idx & 63;
            sx[n * 64 + kk] = (kk < klen) ? xf[n * 510 + k0 + kk] : 0.f;
        }
        __syncthreads();
        float acc[8];
        #pragma unroll
        for (int n = 0; n < 8; ++n) acc[n] = 0.f;
        for (int kk = 0; kk < 64; ++kk) {
            float w = g1lin[(k0 + kk) * 256 + tid];
            #pragma unroll
            for (int n = 0; n < 8; ++n) acc[n] += sx[n * 64 + kk] * w;
        }
        #pragma unroll
        for (int n = 0; n < 8; ++n) ws[WS_HXPART + (b * 8 + n) * 256 + tid] = acc[n];
    } else if (b == 8) {
        // fold q1 = g1le @ a_e ; se1 = ea_ext @ q1
        __shared__ float sea[2048 + 128];
        __shared__ float sae[256], q1[512];
        for (int idx = tid; idx < 2048; idx += 256) sea[idx] = ea[idx];
        sae[tid] = g1ae[tid];
        __syncthreads();
        if (tid < 128) {
            float m = 0.f;
            for (int e = 0; e < 16; ++e) m += sea[e * 128 + tid];
            sea[2048 + tid] = m * (1.f / 16.f);
        }
        __syncthreads();
        for (int o = tid; o < 512; o += 256) {
            int k = o >> 2, hd = o & 3;
            float acc = 0.f;
            for (int c = 0; c < 64; ++c) acc += g1le[k * 256 + hd * 64 + c] * sae[hd * 64 + c];
            q1[o] = acc;
        }
        __syncthreads();
        if (tid < 64) {
            int e = tid >> 2, hd = tid & 3;
            float acc = 0.f;
            for (int k = 0; k < 128; ++k) acc += sea[e * 128 + k] * q1[k * 4 + hd];
            ws[WS_SE1 + tid] = acc;
        } else if (tid < 68) {
            int hd = tid - 64;
            float acc = 0.f;
            for (int k = 0; k < 128; ++k) acc += sea[2048 + k] * q1[k * 4 + hd];
            ws[WS_SE1 + 64 + hd] = acc;
        }
    } else if (b == 9) {
        // edge MLP -> ea_new ; even/odd means ; q2-fold ; se2
        __shared__ float sea[2048];
        __shared__ float tmp[1024];
        __shared__ float ean[17 * 64];
        __shared__ float sq2a[64], sq2[64];
        for (int idx = tid; idx < 2048; idx += 256) sea[idx] = ea[idx];
        if (tid < 64) sq2a[tid] = g2ae[tid];
        __syncthreads();
        for (int o = tid; o < 1024; o += 256) {
            int e = o >> 6, c = o & 63;
            float acc = mb1[c];
            for (int k = 0; k < 128; ++k) acc += sea[e * 128 + k] * mw1[k * 64 + c];
            tmp[o] = fmaxf(acc, 0.f);
        }
        __syncthreads();
        for (int o = tid; o < 1024; o += 256) {
            int e = o >> 6, c = o & 63;
            float acc = mb2[c];
            for (int k = 0; k < 64; ++k) acc += tmp[e * 64 + k] * mw2[k * 64 + c];
            ean[o] = acc;
        }
        __syncthreads();
        if (tid < 64) {
            float m = 0.f;
            for (int e = 0; e < 16; ++e) m += ean[e * 64 + tid];
            ean[1024 + tid] = m * (1.f / 16.f);
        } else if (tid < 128) {
            int c = tid - 64;
            float m = 0.f;
            for (int e = 0; e < 16; e += 2) m += ean[e * 64 + c];
            ws[WS_VM + 64 + c] = m * 0.125f;
        } else if (tid < 192) {
            int c = tid - 128;
            float m = 0.f;
            for (int e = 1; e < 16; e += 2) m += ean[e * 64 + c];
            ws[WS_VM + 128 + c] = m * 0.125f;
        }
        __syncthreads();
        if (tid < 64) {
            float acc = 0.f;
            for (int c = 0; c < 64; ++c) acc += g2le[tid * 64 + c] * sq2a[c];
            sq2[tid] = acc;
        }
        __syncthreads();
        if (tid < 16) {
            float acc = 0.f;
            for (int k = 0; k < 64; ++k) acc += ean[tid * 64 + k] * sq2[k];
            ws[WS_SE2 + tid] = acc;
        } else if (tid == 16) {
            float acc = 0.f;
            for (int k = 0; k < 64; ++k) acc += ean[1024 + k] * sq2[k];
            ws[WS_SE2 + 16] = acc;
        }
    } else if (b == 10) {
        // CNN_1
        __shared__ float t2[160], y1[160], y2[16];
        if (tid < 160) {
            int b_ = tid / 80, ch = (tid % 80) / 10, tt = tid % 10;
            int srow = ((ch & 1) == 0) ? 1 : 5;
            int n = 4 * b_ + (ch >> 1);
            t2[tid] = xft[srow * 80 + n * 10 + tt];
        }
        __syncthreads();
        if (tid < 160) {
            int b_ = tid / 80, co = (tid % 80) / 10, tt = tid % 10;
            float acc = c1b1[co];
            for (int ci = 0; ci < 8; ++ci)
                for (int k = 0; k < 3; ++k) {
                    int p = tt + k - 1;
                    if (p >= 0 && p < 10) acc += t2[b_ * 80 + ci * 10 + p] * c1w1[co * 24 + ci * 3 + k];
                }
            y1[tid] = fmaxf(acc, 0.f);
        }
        __syncthreads();
        if (tid < 16) {
            int b_ = tid >> 3, p = tid & 7;
            float acc = c1b2[0];
            for (int i = 0; i < 10; ++i)
                for (int k = 0; k < 3; ++k) {
                    int q = p + k - 1;
                    if (q >= 0 && q < 8) acc += y1[b_ * 80 + q * 10 + i] * c1w2[i * 3 + k];
                }
            y2[tid] = acc;
        }
        __syncthreads();
        if (tid < 16) ws[WS_XCNN + tid] = fmaxf(y2[tid], 0.f);
    } else {
        // fused tail linear: wf = c2l1w @ c2l2w (+ bf on b11)
        __shared__ float sl2[2560];
        for (int idx = tid; idx < 2560; idx += 256) sl2[idx] = l2w[idx];
        __syncthreads();
        const int m0 = (b - 11) * 32;
        for (int o = tid; o < 320; o += 256) {
            int ml = o / 10, t = o % 10, m = m0 + ml;
            float acc = 0.f;
            for (int j = 0; j < 256; ++j) acc += l1w[m * 256 + j] * sl2[j * 10 + t];
            ws[WS_WF + m * 10 + t] = acc;
        }
        if (b == 11 && tid < 10) {
            float acc = l2b[tid];
            for (int j = 0; j < 256; ++j) acc += l1b[j] * sl2[j * 10 + tid];
            ws[WS_BF + tid] = acc;
        }
    }
}

// ======== K2: wave-parallel GAT chain + per-block tail (16 blocks x 512) =====
__global__ __launch_bounds__(512) void k2_main(
    const float* __restrict__ xft,
    const float* __restrict__ g1lin,
    const float* __restrict__ g1as, const float* __restrict__ g1ad,
    const float* __restrict__ g1b,
    const float* __restrict__ g2lin,
    const float* __restrict__ g2as, const float* __restrict__ g2ad,
    const float* __restrict__ g2b,
    const int* __restrict__ eidx,
    const float* __restrict__ d1w, const float* __restrict__ d1b,
    const float* __restrict__ d2w, const float* __restrict__ d2b,
    const float* __restrict__ d3w, const float* __restrict__ d3b,
    const float* __restrict__ c2w1, const float* __restrict__ c2b1,
    const float* __restrict__ c2w2, const float* __restrict__ c2b2,
    const float* __restrict__ ws, float* __restrict__ out)
{
    __shared__ float sm[16128];
    const int tid = threadIdx.x;
    const int r0 = blockIdx.x * 4;
    int* esrc = (int*)sm + F_ESRC;
    int* edst = (int*)sm + F_EDST;

    // ------------- S0: stage everything; tail weights go to REGISTERS -------------
    float rA[15], rW[12];
    #pragma unroll
    for (int i = 0; i < 15; ++i) {
        int idx = tid + 512 * i;
        int t = idx % 10, rl = (idx / 10) & 3, ii = idx / 40;
        int tau = ii >> 6, iC = ii & 63;
        const float* dw = (tau == 0) ? d1w : (tau == 1) ? d2w : d3w;
        rA[i] = dw[iC * 640 + (r0 + rl) * 10 + t];
    }
    #pragma unroll
    for (int i = 0; i < 12; ++i) rW[i] = c2w2[tid + 512 * i];
    for (int idx = tid; idx < 1600; idx += 512) sm[F_SML + idx] = ws[WS_SMALL + idx];
    for (int idx = tid; idx < 384;  idx += 512) sm[F_SW1 + idx] = c2w1[idx];
    if (tid < 256) {
        sm[F_G1AS + tid] = g1as[tid];
        sm[F_G1AD + tid] = g1ad[tid];
        sm[F_G1B  + tid] = g1b[tid];
        sm[F_GL0  + tid] = g1lin[510 * 256 + tid];
        sm[F_GL1  + tid] = g1lin[511 * 256 + tid];
    } else {
        int j = tid - 256;
        if (j < 64)       { sm[F_G2AS + j] = g2as[j]; sm[F_G2AD + j] = g2ad[j]; sm[F_G2B + j] = g2b[j]; }
        else if (j < 88)  { int i = j - 64;  esrc[i] = (i < 16) ? eidx[i] : i - 16;
                                             edst[i] = (i < 16) ? eidx[16 + i] : i - 16; }
        else if (j < 128) { int i = j - 88;  int rl = i / 10, t = i % 10;
                            sm[F_CIN + rl * 40 + 10 + t] = xft[(r0 + rl) * 10 + t]; }
        else if (j < 160) sm[F_SB1 + j - 128] = c2b1[j - 128];
        else if (j < 224) sm[F_SB2 + j - 160] = c2b2[j - 160];
        else if (j < 236) { int i = j - 224, tau = i / 4, rl = i % 4;
                            const float* db = (tau == 0) ? d1b : (tau == 1) ? d2b : d3b;
                            sm[F_SDB + i] = db[r0 + rl]; }
    }
    __syncthreads();

    // ------------- S1: h = sum of HX partials + CNN columns -------------
    {
        const int j = tid & 255, half = tid >> 8;
        for (int nl = 0; nl < 4; ++nl) {
            int n = half * 4 + nl;
            float acc = 0.f;
            #pragma unroll
            for (int cb = 0; cb < 8; ++cb) acc += ws[WS_HXPART + (cb * 8 + n) * 256 + j];
            acc += sm[F_SML + SM_XCNN + n * 2] * sm[F_GL0 + j]
                 + sm[F_SML + SM_XCNN + n * 2 + 1] * sm[F_GL1 + j];
            sm[F_H + n * 256 + j] = acc;
        }
    }
    __syncthreads();
    // ------------- sc1: ss1/sd1 via 16-lane groups + shuffle reduce -------------
    {
        int p = tid >> 4, g = tid & 15, n = p >> 2, hd = p & 3;
        float aS = 0.f, aD = 0.f;
        #pragma unroll
        for (int cc = 0; cc < 4; ++cc) {
            int c = (((cc + p) & 3) << 4) + g;
            float hv = sm[F_H + n * 256 + hd * 64 + c];
            aS += hv * sm[F_G1AS + hd * 64 + c];
            aD += hv * sm[F_G1AD + hd * 64 + c];
        }
        #pragma unroll
        for (int m = 8; m >= 1; m >>= 1) { aS += __shfl_xor(aS, m); aD += __shfl_xor(aD, m); }
        if (g == 0) { sm[F_SS1 + p] = aS; sm[F_SD1 + p] = aD; }
    }
    __syncthreads();
    if (tid < 96) {   // al1
        int e = tid >> 2, hd = tid & 3;
        float se = (e < 16) ? sm[F_SML + SM_SE1 + tid] : sm[F_SML + SM_SE1 + 64 + hd];
        float s = sm[F_SS1 + esrc[e] * 4 + hd] + sm[F_SD1 + edst[e] * 4 + hd] + se;
        sm[F_AL1 + tid] = (s > 0.f) ? s : 0.2f * s;
    }
    __syncthreads();
    // ------------- stat1: masked max/sum, 16-lane groups -------------
    {
        int p = tid >> 4, g = tid & 15, n = p >> 2, hd = p & 3;
        float v1 = (edst[g] == n) ? sm[F_AL1 + g * 4 + hd] : -1e30f;
        float v2 = (g < 8 && edst[g + 16] == n) ? sm[F_AL1 + (g + 16) * 4 + hd] : -1e30f;
        float mx = fmaxf(v1, v2);
        #pragma unroll
        for (int m = 8; m >= 1; m >>= 1) mx = fmaxf(mx, __shfl_xor(mx, m));
        float ex = expf(v1 - mx) + ((g < 8) ? expf(v2 - mx) : 0.f);
        #pragma unroll
        for (int m = 8; m >= 1; m >>= 1) ex += __shfl_xor(ex, m);
        if (g == 0) { sm[F_MX1 + p] = mx; sm[F_DN1 + p] = ex; }
    }
    __syncthreads();
    if (tid < 96) {   // wt1
        int e = tid >> 2, hd = tid & 3, d = edst[e];
        sm[F_WT1 + tid] = expf(sm[F_AL1 + tid] - sm[F_MX1 + d * 4 + hd]) / (sm[F_DN1 + d * 4 + hd] + 1e-16f);
    }
    __syncthreads();
    if (tid < 256) {  // A1[s][n][hd] = sum of wt over matching edges (branchless)
        int s = tid >> 5, n = (tid >> 2) & 7, hd = tid & 3;
        float acc = 0.f;
        #pragma unroll
        for (int e = 0; e < 24; ++e)
            acc += (edst[e] == n && esrc[e] == s) ? sm[F_WT1 + e * 4 + hd] : 0.f;
        sm[F_A1 + tid] = acc;
    }
    __syncthreads();
    // ------------- x1 = relu(A1 @ h + b): 8 MACs/output -------------
    {
        const int j = tid & 255, half = tid >> 8, hd = j >> 6;
        for (int nl = 0; nl < 4; ++nl) {
            int n = half * 4 + nl;
            float acc = 0.f;
            #pragma unroll
            for (int s = 0; s < 8; ++s)
                acc += sm[F_A1 + s * 32 + n * 4 + hd] * sm[F_H + s * 256 + j];
            sm[F_X1 + n * 256 + j] = fmaxf(acc + sm[F_G1B + j], 0.f);
        }
    }
    __syncthreads();
    // ------------- h2 = x1 @ g2_lin (4-way k-split, coalesced stream) -------------
    {
        const int kc = tid >> 7, sub = (tid >> 6) & 1, c = tid & 63;
        float p0 = 0.f, p1 = 0.f, p2 = 0.f, p3 = 0.f;
        for (int kk = 0; kk < 64; ++kk) {
            int k = kc * 64 + kk;
            float g = g2lin[k * 64 + c];
            p0 += sm[F_X1 + (sub * 4 + 0) * 256 + k] * g;
            p1 += sm[F_X1 + (sub * 4 + 1) * 256 + k] * g;
            p2 += sm[F_X1 + (sub * 4 + 2) * 256 + k] * g;
            p3 += sm[F_X1 + (sub * 4 + 3) * 256 + k] * g;
        }
        sm[F_H2P + kc * 512 + (sub * 4 + 0) * 64 + c] = p0;
        sm[F_H2P + kc * 512 + (sub * 4 + 1) * 64 + c] = p1;
        sm[F_H2P + kc * 512 + (sub * 4 + 2) * 64 + c] = p2;
        sm[F_H2P + kc * 512 + (sub * 4 + 3) * 64 + c] = p3;
    }
    __syncthreads();
    sm[F_H2 + tid] = sm[F_H2P + tid] + sm[F_H2P + 512 + tid]
                   + sm[F_H2P + 1024 + tid] + sm[F_H2P + 1536 + tid];
    __syncthreads();
    // ------------- sc2: per-node full-wave reduce -------------
    {
        int n = tid >> 6, c = tid & 63;
        float hv = sm[F_H2 + n * 64 + c];
        float aS = hv * sm[F_G2AS + c], aD = hv * sm[F_G2AD + c];
        #pragma unroll
        for (int m = 32; m >= 1; m >>= 1) { aS += __shfl_xor(aS, m); aD += __shfl_xor(aD, m); }
        if (c == 0) { sm[F_SS2 + n] = aS; sm[F_SD2 + n] = aD; }
    }
    __syncthreads();
    if (tid < 24) {   // al2
        float se = (tid < 16) ? sm[F_SML + SM_SE2 + tid] : sm[F_SML + SM_SE2 + 16];
        float s = sm[F_SS2 + esrc[tid]] + sm[F_SD2 + edst[tid]] + se;
        sm[F_AL2 + tid] = (s > 0.f) ? s : 0.2f * s;
    }
    __syncthreads();
    if (tid < 256) {  // stat2: 32-lane groups
        int n = tid >> 5, g = tid & 31;
        float v = (g < 24 && edst[g] == n) ? sm[F_AL2 + g] : -1e30f;
        float mx = v;
        #pragma unroll
        for (int m = 16; m >= 1; m >>= 1) mx = fmaxf(mx, __shfl_xor(mx, m));
        float ex = expf(v - mx);
        #pragma unroll
        for (int m = 16; m >= 1; m >>= 1) ex += __shfl_xor(ex, m);
        if (g == 0) { sm[F_MX2 + n] = mx; sm[F_DN2 + n] = ex; }
    }
    __syncthreads();
    if (tid < 24) {   // wt2
        int d = edst[tid];
        sm[F_WT2 + tid] = expf(sm[F_AL2 + tid] - sm[F_MX2 + d]) / (sm[F_DN2 + d] + 1e-16f);
    }
    __syncthreads();
    if (tid < 64) {   // A2
        int n = tid >> 3, s = tid & 7;
        float acc = 0.f;
        #pragma unroll
        for (int e = 0; e < 24; ++e)
            acc += (edst[e] == n && esrc[e] == s) ? sm[F_WT2 + e] : 0.f;
        sm[F_A2 + tid] = acc;
    }
    __syncthreads();
    {   // x2 = relu(A2 @ h2 + b2)
        int n = tid >> 6, c = tid & 63;
        float acc = 0.f;
        #pragma unroll
        for (int s = 0; s < 8; ++s) acc += sm[F_A2 + n * 8 + s] * sm[F_H2 + s * 64 + c];
        sm[F_X2 + n * 64 + c] = fmaxf(acc + sm[F_G2B + c], 0.f);
    }
    __syncthreads();
    if (tid < 64) {   // vm0 = mean_n(x2) -> sml VM[0..64)
        float m = 0.f;
        #pragma unroll
        for (int n = 0; n < 8; ++n) m += sm[F_X2 + n * 64 + tid];
        sm[F_SML + SM_VM + tid] = m * 0.125f;
    }
    __syncthreads();   // ---- front dead ----

    // ------------- TAIL: dump register-staged weights, then CNN_2 -------------
    #pragma unroll
    for (int i = 0; i < 15; ++i) sm[F_SA + tid + 512 * i] = rA[i];
    #pragma unroll
    for (int i = 0; i < 12; ++i) sm[F_SW2 + tid + 512 * i] = rW[i];
    __syncthreads();
    if (tid < 120) {   // deconv: 4 rl x 3 tau x 10 t
        int t = tid % 10, tau = (tid / 10) % 3, rl = tid / 30;
        float acc = sm[F_SDB + tau * 4 + rl];
        for (int i = 0; i < 64; ++i)
            acc += sm[F_SML + SM_VM + tau * 64 + i] * sm[F_SA + ((tau * 64 + i) * 4 + rl) * 10 + t];
        int ch = (tau == 0) ? 0 : (tau + 1);
        sm[F_CIN + rl * 40 + ch * 10 + t] = acc;
    }
    __syncthreads();
    for (int o = tid; o < 1024; o += 512) {   // conv1 (u @ sA[0..1024))
        int rl = o >> 8, co = (o >> 3) & 31, p = o & 7;
        float acc = sm[F_SB1 + co];
        #pragma unroll
        for (int ci = 0; ci < 4; ++ci)
            #pragma unroll
            for (int k = 0; k < 3; ++k)
                acc += sm[F_CIN + rl * 40 + ci * 10 + p + k] * sm[F_SW1 + co * 12 + ci * 3 + k];
        sm[F_SA + o] = acc;
    }
    __syncthreads();
    {   // maxpool(2) (v @ sA[1024..1536))
        int rl = tid >> 7, co = (tid >> 2) & 31, q = tid & 3;
        sm[F_SA + 1024 + tid] = fmaxf(sm[F_SA + rl * 256 + co * 8 + 2 * q],
                                      sm[F_SA + rl * 256 + co * 8 + 2 * q + 1]);
    }
    __syncthreads();
    {   // conv2 + flatten (f @ sA[1536..2048))
        int rl = tid >> 7, m = tid & 127, co2 = m >> 1, p = m & 1;
        float acc = sm[F_SB2 + co2];
        for (int ci = 0; ci < 32; ++ci)
            #pragma unroll
            for (int k = 0; k < 3; ++k)
                acc += sm[F_SA + 1024 + rl * 128 + ci * 4 + p + k] * sm[F_SW2 + co2 * 96 + ci * 3 + k];
        sm[F_SA + 1536 + tid] = acc;
    }
    __syncthreads();
    if (tid < 40) {   // fused (l1->l2) + relu -> out
        int rl = tid / 10, t = tid % 10;
        float acc = sm[F_SML + SM_BF + t];
        for (int m = 0; m < 128; ++m)
            acc += sm[F_SA + 1536 + rl * 128 + m] * sm[F_SML + SM_WF + m * 10 + t];
        out[(r0 + rl) * 10 + t] = fmaxf(acc, 0.f);
    }
}

extern "C" void kernel_launch(void* const* d_in, const int* in_sizes, int n_in,
                              void* d_out, int out_size, void* d_ws, size_t ws_size,
                              hipStream_t stream)
{
    const float* xf    = (const float*)d_in[0];
    const float* xft   = (const float*)d_in[1];
    const float* ea    = (const float*)d_in[2];
    const float* c1w1  = (const float*)d_in[3];
    const float* c1b1  = (const float*)d_in[4];
    const float* c1w2  = (const float*)d_in[5];
    const float* c1b2  = (const float*)d_in[6];
    const float* g1lin = (const float*)d_in[7];
    const float* g1as  = (const float*)d_in[8];
    const float* g1ad  = (const float*)d_in[9];
    const float* g1le  = (const float*)d_in[10];
    const float* g1ae  = (const float*)d_in[11];
    const float* g1b   = (const float*)d_in[12];
    const float* g2lin = (const float*)d_in[13];
    const float* g2as  = (const float*)d_in[14];
    const float* g2ad  = (const float*)d_in[15];
    const float* g2le  = (const float*)d_in[16];
    const float* g2ae  = (const float*)d_in[17];
    const float* g2b   = (const float*)d_in[18];
    const float* mw1   = (const float*)d_in[19];
    const float* mb1   = (const float*)d_in[20];
    const float* mw2   = (const float*)d_in[21];
    const float* mb2   = (const float*)d_in[22];
    const float* d1w   = (const float*)d_in[23];
    const float* d1b   = (const float*)d_in[24];
    const float* d2w   = (const float*)d_in[25];
    const float* d2b   = (const float*)d_in[26];
    const float* d3w   = (const float*)d_in[27];
    const float* d3b   = (const float*)d_in[28];
    const float* c2w1  = (const float*)d_in[29];
    const float* c2b1  = (const float*)d_in[30];
    const float* c2w2  = (const float*)d_in[31];
    const float* c2b2  = (const float*)d_in[32];
    const float* l1w   = (const float*)d_in[33];
    const float* l1b   = (const float*)d_in[34];
    const float* l2w   = (const float*)d_in[35];
    const float* l2b   = (const float*)d_in[36];
    const int*   eidx  = (const int*)d_in[37];
    float* ws  = (float*)d_ws;
    float* out = (float*)d_out;

    hipLaunchKernelGGL(k1_pre, dim3(15), dim3(256), 0, stream,
        xf, xft, ea, c1w1, c1b1, c1w2, c1b2,
        g1lin, g1le, g1ae, mw1, mb1, mw2, mb2,
        g2le, g2ae, l1w, l1b, l2w, l2b, ws);
    hipLaunchKernelGGL(k2_main, dim3(16), dim3(512), 0, stream,
        xft, g1lin, g1as, g1ad, g1b,
        g2lin, g2as, g2ad, g2b, eidx,
        d1w, d1b, d2w, d2b, d3w, d3b,
        c2w1, c2b1, c2w2, c2b2, ws, out);
}